// Round 10
// baseline (869.194 us; speedup 1.0000x reference)
//
#include <hip/hip_runtime.h>
#include <hip/hip_fp16.h>
#include <cmath>

#define DEVI static __device__ __forceinline__

constexpr int HIDn = 128, OUTn = 64;
constexpr int NCn = 50000, NDn = 50000, En = 400000;

// monotonic float->uint mapping for atomicMax on floats (handles signs)
DEVI unsigned fmap(float f) {
  int i = __float_as_int(f);
  return (i < 0) ? ~((unsigned)i) : (((unsigned)i) | 0x80000000u);
}
DEVI float fdecode(unsigned u) {
  int i = (u & 0x80000000u) ? (int)(u & 0x7fffffffu) : (int)(~u);
  return __int_as_float(i);
}

DEVI float tanh_fast(float x) {           // 1 - 2/(e^{2x}+1); saturates correctly
  float e = __expf(2.f * x);
  return 1.f - __fdividef(2.f, e + 1.f);
}

// ---- vectorized 8-wide A-row load + fused transform (value-based) -------
// MODE: 0=plain, 1=elu(x), 2=elu(w2*a+w3*b).  base must be 16B-aligned.
template<int MODE>
DEVI void loadrow8(float* __restrict__ tmp,
                   const float* __restrict__ A, const float* __restrict__ A2,
                   float w2, float w3, size_t base)
{
  const float4* p = (const float4*)(A + base);
  float4 u0 = p[0], u1 = p[1];
  float v[8] = {u0.x, u0.y, u0.z, u0.w, u1.x, u1.y, u1.z, u1.w};
  if (MODE == 2) {
    const float4* q = (const float4*)(A2 + base);
    float4 t0 = q[0], t1 = q[1];
    float vb[8] = {t0.x, t0.y, t0.z, t0.w, t1.x, t1.y, t1.z, t1.w};
    #pragma unroll
    for (int i = 0; i < 8; ++i) v[i] = w2 * v[i] + w3 * vb[i];
  }
  if (MODE >= 1) {
    #pragma unroll
    for (int i = 0; i < 8; ++i) v[i] = (v[i] > 0.f) ? v[i] : (__expf(v[i]) - 1.f);
  }
  #pragma unroll
  for (int i = 0; i < 8; ++i) tmp[i] = v[i];
}

// ------- GEMM: C[N,128] = xform(A)[N,KI] @ W[KI,128] + b; 128x128 tile ---
// 256 threads, 8x8 acc/thread (rows r4..r4+3 & 64+r4.., cols c4.. & 64+c4..)
template<int KI, int MODE>
__global__ __launch_bounds__(256)
void gemm_bias(const float* __restrict__ A, const float* __restrict__ A2,
               const float* __restrict__ wv,
               const float* __restrict__ W, const float* __restrict__ b,
               float* __restrict__ C, int N)
{
  __shared__ float At[32][132];   // A^T chunk: [k][row], 128 rows
  __shared__ float Ws[32][132];   // W chunk:   [k][col], 128 cols
  float w2 = 0.f, w3 = 0.f;
  if (MODE == 2) { w2 = wv[2]; w3 = wv[3]; }
  const int row0 = blockIdx.x * 128;
  const int tid  = threadIdx.x;
  const int r4 = (tid >> 4) << 2;     // 0..60
  const int c4 = (tid & 15) << 2;     // 0..60
  float acc[8][8] = {};

  for (int k0 = 0; k0 < KI; k0 += 32) {
    {
      const int r  = tid >> 1;
      const int kq = (tid & 1) << 4;
      const int row = row0 + r;
      float tmp[16];
      if (row < N) {
        loadrow8<MODE>(tmp,     A, A2, w2, w3, (size_t)row * KI + k0 + kq);
        loadrow8<MODE>(tmp + 8, A, A2, w2, w3, (size_t)row * KI + k0 + kq + 8);
      } else {
        #pragma unroll
        for (int i = 0; i < 16; ++i) tmp[i] = 0.f;
      }
      #pragma unroll
      for (int i = 0; i < 16; ++i) At[kq + i][r] = tmp[i];
    }
    {
      const int k  = tid >> 3;
      const int cq = (tid & 7) << 4;
      const float* wp = W + (size_t)(k0 + k) * 128 + cq;
      *(float4*)&Ws[k][cq]      = *(const float4*)wp;
      *(float4*)&Ws[k][cq + 4]  = *(const float4*)(wp + 4);
      *(float4*)&Ws[k][cq + 8]  = *(const float4*)(wp + 8);
      *(float4*)&Ws[k][cq + 12] = *(const float4*)(wp + 12);
    }
    __syncthreads();
    #pragma unroll
    for (int k = 0; k < 32; ++k) {
      float4 aL = *(const float4*)&At[k][r4];
      float4 aH = *(const float4*)&At[k][r4 + 64];
      float4 wL = *(const float4*)&Ws[k][c4];
      float4 wH = *(const float4*)&Ws[k][c4 + 64];
      float av[8] = {aL.x, aL.y, aL.z, aL.w, aH.x, aH.y, aH.z, aH.w};
      float wq[8] = {wL.x, wL.y, wL.z, wL.w, wH.x, wH.y, wH.z, wH.w};
      #pragma unroll
      for (int i = 0; i < 8; ++i) {
        #pragma unroll
        for (int j = 0; j < 8; ++j) acc[i][j] += av[i] * wq[j];
      }
    }
    __syncthreads();
  }

  #pragma unroll
  for (int i = 0; i < 8; ++i) {
    const int row = row0 + ((i < 4) ? (r4 + i) : (64 + r4 + i - 4));
    if (row >= N) continue;
    #pragma unroll
    for (int j = 0; j < 8; ++j) {
      const int col = (j < 4) ? (c4 + j) : (64 + c4 + j - 4);
      C[(size_t)row * 128 + col] = acc[i][j] + b[col];
    }
  }
}

// ---- all six per-(node,head) attention dots of one layer in one pass ----
DEVI float dot4f(float4 a, float4 b) { return a.x*b.x + a.y*b.y + a.z*b.z + a.w*b.w; }

__global__ void dot6(const float* __restrict__ hc, const float* __restrict__ hd,
                     const float* __restrict__ ascc, const float* __restrict__ adcc,
                     const float* __restrict__ asdc, const float* __restrict__ addc,
                     const float* __restrict__ ascd, const float* __restrict__ adcd,
                     float* __restrict__ scc, float* __restrict__ dcc,
                     float* __restrict__ ddc, float* __restrict__ scd,
                     float* __restrict__ sdc, float* __restrict__ dcd, int N)
{
  int idx = blockIdx.x * blockDim.x + threadIdx.x;
  if (idx >= N * 4) return;
  int n = idx >> 2, hh = idx & 3;
  const float4* hp = (const float4*)(hc + (size_t)n * HIDn + hh * 32);
  const float4* dp = (const float4*)(hd + (size_t)n * HIDn + hh * 32);
  const float4* a1 = (const float4*)(ascc + hh * 32);
  const float4* a2 = (const float4*)(adcc + hh * 32);
  const float4* a3 = (const float4*)(addc + hh * 32);
  const float4* a4 = (const float4*)(ascd + hh * 32);
  const float4* a5 = (const float4*)(asdc + hh * 32);
  const float4* a6 = (const float4*)(adcd + hh * 32);
  float s1 = 0, s2 = 0, s3 = 0, s4 = 0, t1 = 0, t2 = 0;
  #pragma unroll
  for (int i = 0; i < 8; ++i) {
    float4 hv = hp[i];
    s1 += dot4f(hv, a1[i]);
    s2 += dot4f(hv, a2[i]);
    s3 += dot4f(hv, a3[i]);
    s4 += dot4f(hv, a4[i]);
    float4 dv = dp[i];
    t1 += dot4f(dv, a5[i]);
    t2 += dot4f(dv, a6[i]);
  }
  scc[idx] = s1; dcc[idx] = s2; ddc[idx] = s3;
  scd[idx] = s4; sdc[idx] = t1; dcd[idx] = t2;
}

// ================= CSR build, all 3 graphs batched =======================
__global__ void hist3(const int* __restrict__ ei0, const int* __restrict__ ei1,
                      const int* __restrict__ ei2, int* __restrict__ tmpBase)
{
  int gid = blockIdx.x * blockDim.x + threadIdx.x;
  if (gid >= 3 * En) return;
  int g = gid / En, e = gid - g * En;
  const int* ei = (g == 0) ? ei0 : (g == 1) ? ei1 : ei2;
  atomicAdd(&tmpBase[g * 50000 + ei[En + e]], 1);
}

// one block per graph (grid=3, block=1024)
__global__ void scan3(const int* __restrict__ tmpBase, int* __restrict__ offsBase)
{
  const int n = 50000;
  const int* deg = tmpBase + blockIdx.x * 50000;
  int* offs = offsBase + blockIdx.x * 50004;
  __shared__ int wsum[16];
  __shared__ int carry_sh;
  int tid = threadIdx.x;
  if (tid == 0) { carry_sh = 0; offs[0] = 0; }
  __syncthreads();
  const int nw = blockDim.x >> 6;
  int lane = tid & 63, w = tid >> 6;
  for (int base = 0; base < n; base += blockDim.x) {
    int i = base + tid;
    int v = (i < n) ? deg[i] : 0;
    int x = v;
    #pragma unroll
    for (int off = 1; off < 64; off <<= 1) {
      int y = __shfl_up(x, off);
      if (lane >= off) x += y;
    }
    if (lane == 63) wsum[w] = x;
    __syncthreads();
    if (tid == 0) {
      int s = carry_sh;
      for (int ww = 0; ww < nw; ++ww) { int t = wsum[ww]; wsum[ww] = s; s += t; }
      carry_sh = s;
    }
    __syncthreads();
    if (i < n) offs[i + 1] = wsum[w] + x;
    __syncthreads();
  }
}

__global__ void fill3(const int* __restrict__ ei0, const int* __restrict__ ei1,
                      const int* __restrict__ ei2, const int* __restrict__ offsBase,
                      int* __restrict__ cursorBase, int* __restrict__ elistBase)
{
  int gid = blockIdx.x * blockDim.x + threadIdx.x;
  if (gid >= 3 * En) return;
  int g = gid / En, e = gid - g * En;
  const int* ei = (g == 0) ? ei0 : (g == 1) ? ei1 : ei2;
  const int* offs = offsBase + g * 50004;
  int* cursor = cursorBase + g * 50000;
  int* elist = elistBase + (size_t)g * En;
  int s = ei[e], d = ei[En + e];
  int p = atomicAdd(&cursor[d], 1);
  elist[offs[d] + p] = s;
}

// ==== per-dst normalized edge weights (alpha) in fp16, CSR order =========
// thread = (graph, dst): pass1 sums e^l per head, pass2 writes alpha=e/den.
__global__ void edge_w3(const int* __restrict__ offsBase, const int* __restrict__ elistBase,
                        const float* __restrict__ scc, const float* __restrict__ dcc,
                        const float* __restrict__ sdc, const float* __restrict__ ddc,
                        const float* __restrict__ scd, const float* __restrict__ dcd,
                        __half* __restrict__ wcsr)
{
  int gid = blockIdx.x * blockDim.x + threadIdx.x;
  if (gid >= 150000) return;
  int g = gid / 50000, dst = gid - g * 50000;
  const int* offs = offsBase + g * 50004;
  const int* el = elistBase + (size_t)g * En;
  __half* w = wcsr + (size_t)g * En * 4;
  const float* sd = (g == 0) ? scc : (g == 1) ? sdc : scd;
  const float* dd = (g == 0) ? dcc : (g == 1) ? ddc : dcd;
  const float d0 = dd[dst * 4], d1 = dd[dst * 4 + 1], d2 = dd[dst * 4 + 2], d3 = dd[dst * 4 + 3];
  const int i0 = offs[dst], i1 = offs[dst + 1];
  float den0 = 1e-16f, den1 = 1e-16f, den2 = 1e-16f, den3 = 1e-16f;
  for (int i = i0; i < i1; ++i) {
    int s = el[i];
    float4 sv = *(const float4*)(sd + (size_t)s * 4);
    float l0 = sv.x + d0; l0 = fminf(fmaxf(l0, 0.2f * l0), 60.f);
    float l1 = sv.y + d1; l1 = fminf(fmaxf(l1, 0.2f * l1), 60.f);
    float l2 = sv.z + d2; l2 = fminf(fmaxf(l2, 0.2f * l2), 60.f);
    float l3 = sv.w + d3; l3 = fminf(fmaxf(l3, 0.2f * l3), 60.f);
    den0 += __expf(l0); den1 += __expf(l1);
    den2 += __expf(l2); den3 += __expf(l3);
  }
  float inv0 = __fdividef(1.f, den0), inv1 = __fdividef(1.f, den1);
  float inv2 = __fdividef(1.f, den2), inv3 = __fdividef(1.f, den3);
  for (int i = i0; i < i1; ++i) {
    int s = el[i];
    float4 sv = *(const float4*)(sd + (size_t)s * 4);
    float l0 = sv.x + d0; l0 = fminf(fmaxf(l0, 0.2f * l0), 60.f);
    float l1 = sv.y + d1; l1 = fminf(fmaxf(l1, 0.2f * l1), 60.f);
    float l2 = sv.z + d2; l2 = fminf(fmaxf(l2, 0.2f * l2), 60.f);
    float l3 = sv.w + d3; l3 = fminf(fmaxf(l3, 0.2f * l3), 60.f);
    __half2* wp = (__half2*)(w + (size_t)i * 4);
    wp[0] = __floats2half2_rn(__expf(l0) * inv0, __expf(l1) * inv1);
    wp[1] = __floats2half2_rn(__expf(l2) * inv2, __expf(l3) * inv3);
  }
}

// ==== FUSED edge attention, precomputed-alpha variant (pure gather-FMA) ==
struct EdgeOpP {
  const int* offs; const int* elist; const __half* al;
  const float* hsrc; float* out;
};

DEVI void csr_att_pre(const EdgeOpP& op, int dst, int lane)
{
  const int i0 = op.offs[dst], i1 = op.offs[dst + 1];
  const int hB = lane >> 4;
  const float* hsrc = op.hsrc;
  const int* el = op.elist;
  const __half* al = op.al;
  float a0 = 0.f, a1 = 0.f;
  int i = i0;
  for (; i + 4 <= i1; i += 4) {
    int s0 = el[i], s1 = el[i + 1], s2 = el[i + 2], s3 = el[i + 3];
    float w0 = __half2float(al[(size_t)i * 4 + hB]);
    float w1 = __half2float(al[(size_t)(i + 1) * 4 + hB]);
    float w2 = __half2float(al[(size_t)(i + 2) * 4 + hB]);
    float w3 = __half2float(al[(size_t)(i + 3) * 4 + hB]);
    float2 h0 = *(const float2*)(hsrc + (size_t)s0 * HIDn + lane * 2);
    float2 h1 = *(const float2*)(hsrc + (size_t)s1 * HIDn + lane * 2);
    float2 h2 = *(const float2*)(hsrc + (size_t)s2 * HIDn + lane * 2);
    float2 h3 = *(const float2*)(hsrc + (size_t)s3 * HIDn + lane * 2);
    a0 += h0.x * w0 + h1.x * w1 + h2.x * w2 + h3.x * w3;
    a1 += h0.y * w0 + h1.y * w1 + h2.y * w2 + h3.y * w3;
  }
  for (; i < i1; ++i) {
    int s = el[i];
    float w = __half2float(al[(size_t)i * 4 + hB]);
    float2 hv = *(const float2*)(hsrc + (size_t)s * HIDn + lane * 2);
    a0 += hv.x * w;
    a1 += hv.y * w;
  }
  float2 o2;
  o2.x = fmaxf(a0, 0.f);
  o2.y = fmaxf(a1, 0.f);
  *(float2*)(op.out + (size_t)dst * HIDn + lane * 2) = o2;
}

__global__ __launch_bounds__(256)
void csr_att3_pre(EdgeOpP op0, EdgeOpP op1, EdgeOpP op2, int Ndst)
{
  int wave = (blockIdx.x * 256 + threadIdx.x) >> 6;
  if (wave >= Ndst) return;
  const int lane = threadIdx.x & 63;
  if (blockIdx.y == 0)      csr_att_pre(op0, wave, lane);
  else if (blockIdx.y == 1) csr_att_pre(op1, wave, lane);
  else                      csr_att_pre(op2, wave, lane);
}

// ==== inline-weights variant (tier 2) =====================================
struct EdgeOp {
  const int* offs; const int* elist;
  const float* sdot; const float* ddot;
  const float* hsrc; float* out;
};

DEVI void csr_att_body(const EdgeOp& op, int dst, int lane)
{
  const int i0 = op.offs[dst], i1 = op.offs[dst + 1];
  const int hB = lane >> 4;
  const float ddB = op.ddot[dst * 4 + hB];
  const float* hsrc = op.hsrc;
  const float* sdot = op.sdot;
  const int* el = op.elist;
  float den = 0.f, a0 = 0.f, a1 = 0.f;
  int i = i0;
  for (; i + 4 <= i1; i += 4) {
    int s0 = el[i], s1 = el[i + 1], s2 = el[i + 2], s3 = el[i + 3];
    float2 h0 = *(const float2*)(hsrc + (size_t)s0 * HIDn + lane * 2);
    float2 h1 = *(const float2*)(hsrc + (size_t)s1 * HIDn + lane * 2);
    float2 h2 = *(const float2*)(hsrc + (size_t)s2 * HIDn + lane * 2);
    float2 h3 = *(const float2*)(hsrc + (size_t)s3 * HIDn + lane * 2);
    float l0 = sdot[s0 * 4 + hB] + ddB; l0 = fminf(fmaxf(l0, 0.2f * l0), 80.f);
    float l1 = sdot[s1 * 4 + hB] + ddB; l1 = fminf(fmaxf(l1, 0.2f * l1), 80.f);
    float l2 = sdot[s2 * 4 + hB] + ddB; l2 = fminf(fmaxf(l2, 0.2f * l2), 80.f);
    float l3 = sdot[s3 * 4 + hB] + ddB; l3 = fminf(fmaxf(l3, 0.2f * l3), 80.f);
    float e0 = __expf(l0), e1 = __expf(l1), e2 = __expf(l2), e3 = __expf(l3);
    den += (e0 + e1) + (e2 + e3);
    a0 += h0.x * e0 + h1.x * e1 + h2.x * e2 + h3.x * e3;
    a1 += h0.y * e0 + h1.y * e1 + h2.y * e2 + h3.y * e3;
  }
  for (; i < i1; ++i) {
    int s = el[i];
    float2 hv = *(const float2*)(hsrc + (size_t)s * HIDn + lane * 2);
    float lv = sdot[s * 4 + hB] + ddB; lv = fminf(fmaxf(lv, 0.2f * lv), 80.f);
    float e = __expf(lv);
    den += e;
    a0 += hv.x * e;
    a1 += hv.y * e;
  }
  float dinv = __fdividef(1.f, den + 1e-16f);
  float2 o2;
  o2.x = fmaxf(a0 * dinv, 0.f);
  o2.y = fmaxf(a1 * dinv, 0.f);
  *(float2*)(op.out + (size_t)dst * HIDn + lane * 2) = o2;
}

__global__ __launch_bounds__(256)
void csr_att3(EdgeOp op0, EdgeOp op1, EdgeOp op2, int Ndst)
{
  int wave = (blockIdx.x * 256 + threadIdx.x) >> 6;
  if (wave >= Ndst) return;
  const int lane = threadIdx.x & 63;
  if (blockIdx.y == 0)      csr_att_body(op0, wave, lane);
  else if (blockIdx.y == 1) csr_att_body(op1, wave, lane);
  else                      csr_att_body(op2, wave, lane);
}

// ---- fallback path (atomic scatter), tier 3 ------------------------------
__global__ void edge_logit_max(const int* __restrict__ ei,
                               const float* __restrict__ sdot,
                               const float* __restrict__ ddot,
                               unsigned* __restrict__ m)
{
  int e = blockIdx.x * blockDim.x + threadIdx.x;
  if (e >= En) return;
  int s = ei[e], d = ei[En + e];
  #pragma unroll
  for (int hh = 0; hh < 4; ++hh) {
    float l = sdot[s * 4 + hh] + ddot[d * 4 + hh];
    l = (l > 0.f) ? l : 0.2f * l;
    atomicMax(&m[d * 4 + hh], fmap(l));
  }
}

__global__ void edge_exp_sum(const int* __restrict__ ei,
                             const float* __restrict__ sdot,
                             const float* __restrict__ ddot,
                             const unsigned* __restrict__ m,
                             float* __restrict__ sden,
                             float* __restrict__ ebuf)
{
  int e = blockIdx.x * blockDim.x + threadIdx.x;
  if (e >= En) return;
  int s = ei[e], d = ei[En + e];
  #pragma unroll
  for (int hh = 0; hh < 4; ++hh) {
    float l = sdot[s * 4 + hh] + ddot[d * 4 + hh];
    l = (l > 0.f) ? l : 0.2f * l;
    float ex = expf(fminf(l - fdecode(m[d * 4 + hh]), 0.f));
    ebuf[e * 4 + hh] = ex;
    atomicAdd(&sden[d * 4 + hh], ex);
  }
}

__global__ __launch_bounds__(256)
void edge_scatter(const int* __restrict__ ei, const float* __restrict__ hsrc,
                  const float* __restrict__ ebuf, const float* __restrict__ sden,
                  float* __restrict__ out)
{
  int gid  = blockIdx.x * 256 + threadIdx.x;
  int e    = gid >> 6;
  if (e >= En) return;
  int lane = gid & 63;
  int s = ei[e], d = ei[En + e];
  #pragma unroll
  for (int half = 0; half < 2; ++half) {
    int c  = lane + half * 64;
    int hh = c >> 5;
    float alpha = ebuf[e * 4 + hh] / (sden[d * 4 + hh] + 1e-16f);
    atomicAdd(&out[(size_t)d * HIDn + c], hsrc[(size_t)s * HIDn + c] * alpha);
  }
}

__global__ void relu_k(float* __restrict__ x, int n)
{
  int i = blockIdx.x * blockDim.x + threadIdx.x;
  if (i < n) x[i] = fmaxf(x[i], 0.f);
}

// ---- semantic-attention score, 128x128 tile, 8x8 acc --------------------
// grid (ceil(N/128), 2 inputs)
__global__ __launch_bounds__(256)
void score_gemm(const float* __restrict__ oA, const float* __restrict__ oB,
                const float* __restrict__ kW, const float* __restrict__ kb,
                const float* __restrict__ q, int N, float* __restrict__ slots)
{
  __shared__ float At[32][132];
  __shared__ float Ws[32][132];
  __shared__ float partw[4];
  const float* o = blockIdx.y ? oB : oA;
  const int row0 = blockIdx.x * 128;
  const int tid  = threadIdx.x;
  const int r4 = (tid >> 4) << 2;
  const int c4 = (tid & 15) << 2;
  float acc[8][8] = {};

  for (int k0 = 0; k0 < 128; k0 += 32) {
    {
      const int r  = tid >> 1;
      const int kq = (tid & 1) << 4;
      const int row = row0 + r;
      float tmp[16];
      if (row < N) {
        loadrow8<0>(tmp,     o, nullptr, 0.f, 0.f, (size_t)row * HIDn + k0 + kq);
        loadrow8<0>(tmp + 8, o, nullptr, 0.f, 0.f, (size_t)row * HIDn + k0 + kq + 8);
      } else {
        #pragma unroll
        for (int i = 0; i < 16; ++i) tmp[i] = 0.f;
      }
      #pragma unroll
      for (int i = 0; i < 16; ++i) At[kq + i][r] = tmp[i];
    }
    {
      const int k  = tid >> 3;
      const int cq = (tid & 7) << 4;
      const float* wp = kW + (size_t)(k0 + k) * 128 + cq;
      *(float4*)&Ws[k][cq]      = *(const float4*)wp;
      *(float4*)&Ws[k][cq + 4]  = *(const float4*)(wp + 4);
      *(float4*)&Ws[k][cq + 8]  = *(const float4*)(wp + 8);
      *(float4*)&Ws[k][cq + 12] = *(const float4*)(wp + 12);
    }
    __syncthreads();
    #pragma unroll
    for (int k = 0; k < 32; ++k) {
      float4 aL = *(const float4*)&At[k][r4];
      float4 aH = *(const float4*)&At[k][r4 + 64];
      float4 wL = *(const float4*)&Ws[k][c4];
      float4 wH = *(const float4*)&Ws[k][c4 + 64];
      float av[8] = {aL.x, aL.y, aL.z, aL.w, aH.x, aH.y, aH.z, aH.w};
      float wq[8] = {wL.x, wL.y, wL.z, wL.w, wH.x, wH.y, wH.z, wH.w};
      #pragma unroll
      for (int i = 0; i < 8; ++i) {
        #pragma unroll
        for (int j = 0; j < 8; ++j) acc[i][j] += av[i] * wq[j];
      }
    }
    __syncthreads();
  }

  float sum = 0.f;
  #pragma unroll
  for (int i = 0; i < 8; ++i) {
    int row = row0 + ((i < 4) ? (r4 + i) : (64 + r4 + i - 4));
    if (row >= N) continue;
    #pragma unroll
    for (int j = 0; j < 8; ++j) {
      int col = (j < 4) ? (c4 + j) : (64 + c4 + j - 4);
      sum += q[col] * tanh_fast(acc[i][j] + kb[col]);
    }
  }
  #pragma unroll
  for (int off = 32; off > 0; off >>= 1) sum += __shfl_down(sum, off);
  int wid = tid >> 6, lane = tid & 63;
  if (lane == 0) partw[wid] = sum;
  __syncthreads();
  if (tid == 0)
    atomicAdd(&slots[blockIdx.y],
              (partw[0] + partw[1] + partw[2] + partw[3]) * (1.f / (float)N));
}

__global__ void softmax2_kernel(float* sb)   // sb[0],sb[1] -> weights sb[2],sb[3]
{
  float s0 = sb[0], s1 = sb[1];
  float mx = fmaxf(s0, s1);
  float e0 = expf(s0 - mx), e1 = expf(s1 - mx);
  float inv = 1.f / (e0 + e1);
  sb[2] = e0 * inv;
  sb[3] = e1 * inv;
}

// ---- final projection, 128x64 tile, 8x4 acc, fused transform ------------
template<int MODE, bool NORM>
__global__ __launch_bounds__(256)
void proj_gemm(const float* __restrict__ fa, const float* __restrict__ fb,
               const float* __restrict__ wv,
               const float* __restrict__ pW, const float* __restrict__ pb,
               float* __restrict__ out, int N)
{
  __shared__ float At[32][132];
  __shared__ float Ws[32][68];
  float w2 = 0.f, w3 = 0.f;
  if (MODE == 2) { w2 = wv[2]; w3 = wv[3]; }
  const int row0 = blockIdx.x * 128;
  const int tid  = threadIdx.x;
  const int r0 = (tid >> 4) << 3;
  const int c0 = (tid & 15) << 2;     // 64 cols
  float acc[8][4] = {};

  for (int k0 = 0; k0 < 128; k0 += 32) {
    {
      const int r  = tid >> 1;
      const int kq = (tid & 1) << 4;
      const int row = row0 + r;
      float tmp[16];
      if (row < N) {
        loadrow8<MODE>(tmp,     fa, fb, w2, w3, (size_t)row * HIDn + k0 + kq);
        loadrow8<MODE>(tmp + 8, fa, fb, w2, w3, (size_t)row * HIDn + k0 + kq + 8);
      } else {
        #pragma unroll
        for (int i = 0; i < 16; ++i) tmp[i] = 0.f;
      }
      #pragma unroll
      for (int i = 0; i < 16; ++i) At[kq + i][r] = tmp[i];
    }
    {
      const int k  = tid >> 3;
      const int cq = (tid & 7) << 3;
      const float* wp = pW + (size_t)(k0 + k) * OUTn + cq;
      *(float4*)&Ws[k][cq]     = *(const float4*)wp;
      *(float4*)&Ws[k][cq + 4] = *(const float4*)(wp + 4);
    }
    __syncthreads();
    #pragma unroll
    for (int k = 0; k < 32; ++k) {
      float4 a0v = *(const float4*)&At[k][r0];
      float4 a1v = *(const float4*)&At[k][r0 + 4];
      float4 wv4 = *(const float4*)&Ws[k][c0];
      float av[8] = {a0v.x, a0v.y, a0v.z, a0v.w, a1v.x, a1v.y, a1v.z, a1v.w};
      float wq[4] = {wv4.x, wv4.y, wv4.z, wv4.w};
      #pragma unroll
      for (int i = 0; i < 8; ++i) {
        #pragma unroll
        for (int j = 0; j < 4; ++j) acc[i][j] += av[i] * wq[j];
      }
    }
    __syncthreads();
  }

  float a[8][4];
  #pragma unroll
  for (int i = 0; i < 8; ++i)
    #pragma unroll
    for (int j = 0; j < 4; ++j) a[i][j] = acc[i][j] + pb[c0 + j];

  if (NORM) {
    #pragma unroll
    for (int i = 0; i < 8; ++i) {
      float ss = a[i][0]*a[i][0] + a[i][1]*a[i][1] + a[i][2]*a[i][2] + a[i][3]*a[i][3];
      #pragma unroll
      for (int off = 1; off < 16; off <<= 1) ss += __shfl_xor(ss, off);
      float inv = 1.f / fmaxf(sqrtf(ss), 1e-12f);
      #pragma unroll
      for (int j = 0; j < 4; ++j) a[i][j] *= inv;
    }
  }

  #pragma unroll
  for (int i = 0; i < 8; ++i) {
    int row = row0 + r0 + i;
    if (row >= N) continue;
    #pragma unroll
    for (int j = 0; j < 4; ++j)
      out[(size_t)row * OUTn + c0 + j] = a[i][j];
  }
}

// ---- fallback edge-op dispatcher (tier 3) -------------------------------
static void run_edge_fb(hipStream_t stream, const int* ei,
                        const float* sdot, const float* ddot, const float* hsrc,
                        float* outb, int Ndst,
                        unsigned* mbuf, float* sden, float* ebuf)
{
  hipMemsetAsync(mbuf, 0, (size_t)Ndst * 4 * sizeof(unsigned), stream);
  edge_logit_max<<<(En + 255) / 256, 256, 0, stream>>>(ei, sdot, ddot, mbuf);
  hipMemsetAsync(sden, 0, (size_t)Ndst * 4 * sizeof(float), stream);
  edge_exp_sum<<<(En + 255) / 256, 256, 0, stream>>>(ei, sdot, ddot, mbuf, sden, ebuf);
  hipMemsetAsync(outb, 0, (size_t)Ndst * HIDn * sizeof(float), stream);
  edge_scatter<<<((size_t)En * 64 + 255) / 256, 256, 0, stream>>>(ei, hsrc, ebuf, sden, outb);
  relu_k<<<((size_t)Ndst * HIDn + 255) / 256, 256, 0, stream>>>(outb, Ndst * HIDn);
}

extern "C" void kernel_launch(void* const* d_in, const int* in_sizes, int n_in,
                              void* d_out, int out_size, void* d_ws, size_t ws_size,
                              hipStream_t stream)
{
  const float* xc    = (const float*)d_in[0];
  const float* xd    = (const float*)d_in[1];
  const int*   ei_cc = (const int*)d_in[2];
  const int*   ei_dc = (const int*)d_in[3];
  const int*   ei_cd = (const int*)d_in[4];
  const float* W1c = (const float*)d_in[5];  const float* b1c = (const float*)d_in[6];
  const float* W1d = (const float*)d_in[7];  const float* b1d = (const float*)d_in[8];
  const float* a1s_cc = (const float*)d_in[9];  const float* a1d_cc = (const float*)d_in[10];
  const float* a1s_dc = (const float*)d_in[11]; const float* a1d_dc = (const float*)d_in[12];
  const float* a1s_cd = (const float*)d_in[13]; const float* a1d_cd = (const float*)d_in[14];
  const float* k1W = (const float*)d_in[15]; const float* k1b = (const float*)d_in[16];
  const float* q1  = (const float*)d_in[17];
  const float* W2c = (const float*)d_in[18]; const float* b2c = (const float*)d_in[19];
  const float* W2d = (const float*)d_in[20]; const float* b2d = (const float*)d_in[21];
  const float* a2s_cc = (const float*)d_in[22]; const float* a2d_cc = (const float*)d_in[23];
  const float* a2s_dc = (const float*)d_in[24]; const float* a2d_dc = (const float*)d_in[25];
  const float* a2s_cd = (const float*)d_in[26]; const float* a2d_cd = (const float*)d_in[27];
  const float* k2W = (const float*)d_in[28]; const float* k2b = (const float*)d_in[29];
  const float* q2  = (const float*)d_in[30];
  const float* pW  = (const float*)d_in[31]; const float* pb  = (const float*)d_in[32];

  // ---------------- workspace layout (fp32) ----------------
  float* ws = (float*)d_ws;
  const size_t NB = (size_t)NCn * HIDn;           // 6,400,000 floats per node buffer
  float* B0 = ws;
  float* B1 = ws + NB;
  float* B2 = ws + 2 * NB;
  float* B3 = ws + 3 * NB;
  float* B4 = ws + 4 * NB;
  float* sml = ws + 5 * NB;
  // six dot arrays (N*4 each)
  float* scc = sml;
  float* dcc = sml + 200000;
  float* ddc = sml + 400000;
  float* scd = sml + 600000;
  float* sdc = sml + 800000;
  float* dcd = sml + 1000000;
  float* scoreB = sml + 1200000;                 // [s0,s1,w0,w1, s0',s1',w0',w1']
  float* R0 = sml + 1200016;                     // CSR region (or fallback temps)
  // CSR sub-layout: offs 150,012 ints | elist 1,200,000 ints | tmp 150,000 ints | wcsr 4,800,000 halves
  int*  R0i = (int*)R0;
  int*    offsBase  = R0i;
  int*    elistBase = R0i + 150012;
  int*    tmpBase   = R0i + 1350012;
  __half* wcsrBase  = (__half*)(R0i + 1500012);
  // fallback temps overlay
  unsigned* mbuf = (unsigned*)R0;                // N*4
  float*    sden = R0 + 200000;                  // N*4
  float*    ebuf = R0 + 400000;                  // E*4

  const size_t REQ1 = 5 * NB + 1200016 + 1500012 + 2400000;   // 37,100,028 fl = 148.4 MB
  const size_t REQ2 = 5 * NB + 1200016 + 1500012;             // 34,700,028 fl = 138.8 MB
  const bool tier1 = ws_size >= REQ1 * sizeof(float);
  const bool tier2 = !tier1 && ws_size >= REQ2 * sizeof(float);
  const bool useCsr = tier1 || tier2;

  if (useCsr) {
    hipMemsetAsync(tmpBase, 0, 150000 * sizeof(int), stream);
    hist3<<<(3 * En + 255) / 256, 256, 0, stream>>>(ei_cc, ei_dc, ei_cd, tmpBase);
    scan3<<<3, 1024, 0, stream>>>(tmpBase, offsBase);
    hipMemsetAsync(tmpBase, 0, 150000 * sizeof(int), stream);
    fill3<<<(3 * En + 255) / 256, 256, 0, stream>>>(ei_cc, ei_dc, ei_cd,
                                                    offsBase, tmpBase, elistBase);
  }

  hipMemsetAsync(scoreB, 0, 8 * sizeof(float), stream);

  const int NT128 = (NCn + 127) / 128;
  const int dotGrid = (NCn * 4 + 255) / 256;
  const int* offs0 = offsBase;
  const int* offs1 = offsBase + 50004;
  const int* offs2 = offsBase + 100008;
  const int* el0 = elistBase;
  const int* el1 = elistBase + En;
  const int* el2 = elistBase + 2 * (size_t)En;
  __half* wc0 = wcsrBase;
  __half* wc1 = wcsrBase + (size_t)En * 4;
  __half* wc2 = wcsrBase + (size_t)En * 8;

  // per-layer edge-attention dispatcher
  auto edge_layer = [&](float* hc, float* hd, float* oCC, float* oDC, float* oCD) {
    if (tier1) {
      edge_w3<<<(150000 + 255) / 256, 256, 0, stream>>>(offsBase, elistBase,
                                                        scc, dcc, sdc, ddc, scd, dcd, wcsrBase);
      EdgeOpP p0{offs0, el0, wc0, hc, oCC};
      EdgeOpP p1{offs1, el1, wc1, hd, oDC};
      EdgeOpP p2{offs2, el2, wc2, hc, oCD};
      csr_att3_pre<<<dim3((NCn + 3) / 4, 3), 256, 0, stream>>>(p0, p1, p2, NCn);
    } else if (tier2) {
      EdgeOp o0{offs0, el0, scc, dcc, hc, oCC};
      EdgeOp o1{offs1, el1, sdc, ddc, hd, oDC};
      EdgeOp o2{offs2, el2, scd, dcd, hc, oCD};
      csr_att3<<<dim3((NCn + 3) / 4, 3), 256, 0, stream>>>(o0, o1, o2, NCn);
    } else {
      run_edge_fb(stream, ei_cc, scc, dcc, hc, oCC, NCn, mbuf, sden, ebuf);
      run_edge_fb(stream, ei_dc, sdc, ddc, hd, oDC, NCn, mbuf, sden, ebuf);
      run_edge_fb(stream, ei_cd, scd, dcd, hc, oCD, NDn, mbuf, sden, ebuf);
    }
  };

  // ---------------- layer 1 ----------------
  gemm_bias<256, 0><<<NT128, 256, 0, stream>>>(xc, nullptr, nullptr, W1c, b1c, B0, NCn);
  gemm_bias<256, 0><<<NT128, 256, 0, stream>>>(xd, nullptr, nullptr, W1d, b1d, B1, NDn);

  dot6<<<dotGrid, 256, 0, stream>>>(B0, B1, a1s_cc, a1d_cc, a1s_dc, a1d_dc, a1s_cd, a1d_cd,
                                    scc, dcc, ddc, scd, sdc, dcd, NCn);
  edge_layer(B0, B1, B2, B3, B4);

  score_gemm<<<dim3(NT128, 2), 256, 0, stream>>>(B2, B3, k1W, k1b, q1, NCn, scoreB);
  softmax2_kernel<<<1, 1, 0, stream>>>(scoreB);

  // ---------------- layer 2 (combine/elu fused into A-loads) ----------------
  gemm_bias<128, 2><<<NT128, 256, 0, stream>>>(B2, B3, scoreB, W2c, b2c, B0, NCn);
  gemm_bias<128, 1><<<NT128, 256, 0, stream>>>(B4, nullptr, nullptr, W2d, b2d, B1, NDn);

  dot6<<<dotGrid, 256, 0, stream>>>(B0, B1, a2s_cc, a2d_cc, a2s_dc, a2d_dc, a2s_cd, a2d_cd,
                                    scc, dcc, ddc, scd, sdc, dcd, NCn);
  edge_layer(B0, B1, B2, B3, B4);

  score_gemm<<<dim3(NT128, 2), 256, 0, stream>>>(B2, B3, k2W, k2b, q2, NCn, scoreB + 4);
  softmax2_kernel<<<1, 1, 0, stream>>>(scoreB + 4);

  // ---------------- projection (+combine/elu fused) ----------------
  proj_gemm<2, true ><<<NT128, 256, 0, stream>>>(B2, B3, scoreB + 4, pW, pb, (float*)d_out, NCn);
  proj_gemm<1, false><<<NT128, 256, 0, stream>>>(B4, nullptr, nullptr, pW, pb,
                                                 (float*)d_out + (size_t)NCn * OUTn, NDn);
}

// Round 11
// 803.078 us; speedup vs baseline: 1.0823x; 1.0823x over previous
//
#include <hip/hip_runtime.h>
#include <hip/hip_fp16.h>
#include <cmath>

#define DEVI static __device__ __forceinline__

constexpr int HIDn = 128, OUTn = 64;
constexpr int NCn = 50000, NDn = 50000, En = 400000;

// monotonic float->uint mapping for atomicMax on floats (handles signs)
DEVI unsigned fmap(float f) {
  int i = __float_as_int(f);
  return (i < 0) ? ~((unsigned)i) : (((unsigned)i) | 0x80000000u);
}
DEVI float fdecode(unsigned u) {
  int i = (u & 0x80000000u) ? (int)(u & 0x7fffffffu) : (int)(~u);
  return __int_as_float(i);
}

DEVI float tanh_fast(float x) {           // 1 - 2/(e^{2x}+1); saturates correctly
  float e = __expf(2.f * x);
  return 1.f - __fdividef(2.f, e + 1.f);
}

// ---- vectorized 8-wide A-row load + fused transform (value-based) -------
// MODE: 0=plain, 1=elu(x), 2=elu(w2*a+w3*b).  base must be 16B-aligned.
template<int MODE>
DEVI void loadrow8(float* __restrict__ tmp,
                   const float* __restrict__ A, const float* __restrict__ A2,
                   float w2, float w3, size_t base)
{
  const float4* p = (const float4*)(A + base);
  float4 u0 = p[0], u1 = p[1];
  float v[8] = {u0.x, u0.y, u0.z, u0.w, u1.x, u1.y, u1.z, u1.w};
  if (MODE == 2) {
    const float4* q = (const float4*)(A2 + base);
    float4 t0 = q[0], t1 = q[1];
    float vb[8] = {t0.x, t0.y, t0.z, t0.w, t1.x, t1.y, t1.z, t1.w};
    #pragma unroll
    for (int i = 0; i < 8; ++i) v[i] = w2 * v[i] + w3 * vb[i];
  }
  if (MODE >= 1) {
    #pragma unroll
    for (int i = 0; i < 8; ++i) v[i] = (v[i] > 0.f) ? v[i] : (__expf(v[i]) - 1.f);
  }
  #pragma unroll
  for (int i = 0; i < 8; ++i) tmp[i] = v[i];
}

// ------- GEMM: C[N,KO] = xform(A)[N,KI] @ W[KI,KO] + b; 128x64 tile ------
// 256 threads, 8x4 acc/thread. grid = (ceil(N/128), KO/64).
template<int KI, int MODE>
__global__ __launch_bounds__(256)
void gemm_bias(const float* __restrict__ A, const float* __restrict__ A2,
               const float* __restrict__ wv,
               const float* __restrict__ W, const float* __restrict__ b,
               float* __restrict__ C, int N, int KO)
{
  __shared__ float At[32][132];   // A^T chunk: [k][row], 128 rows
  __shared__ float Ws[32][68];    // W chunk:   [k][col], 64 cols
  float w2 = 0.f, w3 = 0.f;
  if (MODE == 2) { w2 = wv[2]; w3 = wv[3]; }
  const int row0 = blockIdx.x * 128;
  const int col0 = blockIdx.y * 64;
  const int tid  = threadIdx.x;
  const int r0 = (tid >> 4) << 3;     // 0..120 step 8
  const int c0 = (tid & 15) << 2;     // 0..60  step 4
  float acc[8][4] = {};

  for (int k0 = 0; k0 < KI; k0 += 32) {
    {
      const int r  = tid >> 1;
      const int kq = (tid & 1) << 4;
      const int row = row0 + r;
      float tmp[16];
      if (row < N) {
        loadrow8<MODE>(tmp,     A, A2, w2, w3, (size_t)row * KI + k0 + kq);
        loadrow8<MODE>(tmp + 8, A, A2, w2, w3, (size_t)row * KI + k0 + kq + 8);
      } else {
        #pragma unroll
        for (int i = 0; i < 16; ++i) tmp[i] = 0.f;
      }
      #pragma unroll
      for (int i = 0; i < 16; ++i) At[kq + i][r] = tmp[i];
    }
    {
      const int k  = tid >> 3;
      const int cq = (tid & 7) << 3;
      const float* wp = W + (size_t)(k0 + k) * KO + col0 + cq;
      *(float4*)&Ws[k][cq]     = *(const float4*)wp;
      *(float4*)&Ws[k][cq + 4] = *(const float4*)(wp + 4);
    }
    __syncthreads();
    #pragma unroll
    for (int k = 0; k < 32; ++k) {
      float4 a0v = *(const float4*)&At[k][r0];
      float4 a1v = *(const float4*)&At[k][r0 + 4];
      float4 wv4 = *(const float4*)&Ws[k][c0];
      float av[8] = {a0v.x, a0v.y, a0v.z, a0v.w, a1v.x, a1v.y, a1v.z, a1v.w};
      float wq[4] = {wv4.x, wv4.y, wv4.z, wv4.w};
      #pragma unroll
      for (int i = 0; i < 8; ++i) {
        #pragma unroll
        for (int j = 0; j < 4; ++j) acc[i][j] += av[i] * wq[j];
      }
    }
    __syncthreads();
  }

  #pragma unroll
  for (int i = 0; i < 8; ++i) {
    const int row = row0 + r0 + i;
    if (row >= N) continue;
    #pragma unroll
    for (int j = 0; j < 4; ++j) {
      const int col = col0 + c0 + j;
      C[(size_t)row * KO + col] = acc[i][j] + b[col];
    }
  }
}

// ---- all six per-(node,head) attention dots of one layer in one pass ----
DEVI float dot4f(float4 a, float4 b) { return a.x*b.x + a.y*b.y + a.z*b.z + a.w*b.w; }

__global__ void dot6(const float* __restrict__ hc, const float* __restrict__ hd,
                     const float* __restrict__ ascc, const float* __restrict__ adcc,
                     const float* __restrict__ asdc, const float* __restrict__ addc,
                     const float* __restrict__ ascd, const float* __restrict__ adcd,
                     float* __restrict__ scc, float* __restrict__ dcc,
                     float* __restrict__ ddc, float* __restrict__ scd,
                     float* __restrict__ sdc, float* __restrict__ dcd, int N)
{
  int idx = blockIdx.x * blockDim.x + threadIdx.x;
  if (idx >= N * 4) return;
  int n = idx >> 2, hh = idx & 3;
  const float4* hp = (const float4*)(hc + (size_t)n * HIDn + hh * 32);
  const float4* dp = (const float4*)(hd + (size_t)n * HIDn + hh * 32);
  const float4* a1 = (const float4*)(ascc + hh * 32);
  const float4* a2 = (const float4*)(adcc + hh * 32);
  const float4* a3 = (const float4*)(addc + hh * 32);
  const float4* a4 = (const float4*)(ascd + hh * 32);
  const float4* a5 = (const float4*)(asdc + hh * 32);
  const float4* a6 = (const float4*)(adcd + hh * 32);
  float s1 = 0, s2 = 0, s3 = 0, s4 = 0, t1 = 0, t2 = 0;
  #pragma unroll
  for (int i = 0; i < 8; ++i) {
    float4 hv = hp[i];
    s1 += dot4f(hv, a1[i]);
    s2 += dot4f(hv, a2[i]);
    s3 += dot4f(hv, a3[i]);
    s4 += dot4f(hv, a4[i]);
    float4 dv = dp[i];
    t1 += dot4f(dv, a5[i]);
    t2 += dot4f(dv, a6[i]);
  }
  scc[idx] = s1; dcc[idx] = s2; ddc[idx] = s3;
  scd[idx] = s4; sdc[idx] = t1; dcd[idx] = t2;
}

// ================= CSR build, all 3 graphs batched =======================
__global__ void hist3(const int* __restrict__ ei0, const int* __restrict__ ei1,
                      const int* __restrict__ ei2, int* __restrict__ tmpBase)
{
  int gid = blockIdx.x * blockDim.x + threadIdx.x;
  if (gid >= 3 * En) return;
  int g = gid / En, e = gid - g * En;
  const int* ei = (g == 0) ? ei0 : (g == 1) ? ei1 : ei2;
  atomicAdd(&tmpBase[g * 50000 + ei[En + e]], 1);
}

// one block per graph (grid=3, block=1024)
__global__ void scan3(const int* __restrict__ tmpBase, int* __restrict__ offsBase)
{
  const int n = 50000;
  const int* deg = tmpBase + blockIdx.x * 50000;
  int* offs = offsBase + blockIdx.x * 50004;
  __shared__ int wsum[16];
  __shared__ int carry_sh;
  int tid = threadIdx.x;
  if (tid == 0) { carry_sh = 0; offs[0] = 0; }
  __syncthreads();
  const int nw = blockDim.x >> 6;
  int lane = tid & 63, w = tid >> 6;
  for (int base = 0; base < n; base += blockDim.x) {
    int i = base + tid;
    int v = (i < n) ? deg[i] : 0;
    int x = v;
    #pragma unroll
    for (int off = 1; off < 64; off <<= 1) {
      int y = __shfl_up(x, off);
      if (lane >= off) x += y;
    }
    if (lane == 63) wsum[w] = x;
    __syncthreads();
    if (tid == 0) {
      int s = carry_sh;
      for (int ww = 0; ww < nw; ++ww) { int t = wsum[ww]; wsum[ww] = s; s += t; }
      carry_sh = s;
    }
    __syncthreads();
    if (i < n) offs[i + 1] = wsum[w] + x;
    __syncthreads();
  }
}

__global__ void fill3(const int* __restrict__ ei0, const int* __restrict__ ei1,
                      const int* __restrict__ ei2, const int* __restrict__ offsBase,
                      int* __restrict__ cursorBase, int* __restrict__ elistBase)
{
  int gid = blockIdx.x * blockDim.x + threadIdx.x;
  if (gid >= 3 * En) return;
  int g = gid / En, e = gid - g * En;
  const int* ei = (g == 0) ? ei0 : (g == 1) ? ei1 : ei2;
  const int* offs = offsBase + g * 50004;
  int* cursor = cursorBase + g * 50000;
  int* elist = elistBase + (size_t)g * En;
  int s = ei[e], d = ei[En + e];
  int p = atomicAdd(&cursor[d], 1);
  elist[offs[d] + p] = s;
}

// ==== per-dst normalized edge weights (alpha) in fp16, CSR order =========
__global__ void edge_w3(const int* __restrict__ offsBase, const int* __restrict__ elistBase,
                        const float* __restrict__ scc, const float* __restrict__ dcc,
                        const float* __restrict__ sdc, const float* __restrict__ ddc,
                        const float* __restrict__ scd, const float* __restrict__ dcd,
                        __half* __restrict__ wcsr)
{
  int gid = blockIdx.x * blockDim.x + threadIdx.x;
  if (gid >= 150000) return;
  int g = gid / 50000, dst = gid - g * 50000;
  const int* offs = offsBase + g * 50004;
  const int* el = elistBase + (size_t)g * En;
  __half* w = wcsr + (size_t)g * En * 4;
  const float* sd = (g == 0) ? scc : (g == 1) ? sdc : scd;
  const float* dd = (g == 0) ? dcc : (g == 1) ? ddc : dcd;
  const float d0 = dd[dst * 4], d1 = dd[dst * 4 + 1], d2 = dd[dst * 4 + 2], d3 = dd[dst * 4 + 3];
  const int i0 = offs[dst], i1 = offs[dst + 1];
  float den0 = 1e-16f, den1 = 1e-16f, den2 = 1e-16f, den3 = 1e-16f;
  for (int i = i0; i < i1; ++i) {
    int s = el[i];
    float4 sv = *(const float4*)(sd + (size_t)s * 4);
    float l0 = sv.x + d0; l0 = fminf(fmaxf(l0, 0.2f * l0), 60.f);
    float l1 = sv.y + d1; l1 = fminf(fmaxf(l1, 0.2f * l1), 60.f);
    float l2 = sv.z + d2; l2 = fminf(fmaxf(l2, 0.2f * l2), 60.f);
    float l3 = sv.w + d3; l3 = fminf(fmaxf(l3, 0.2f * l3), 60.f);
    den0 += __expf(l0); den1 += __expf(l1);
    den2 += __expf(l2); den3 += __expf(l3);
  }
  float inv0 = __fdividef(1.f, den0), inv1 = __fdividef(1.f, den1);
  float inv2 = __fdividef(1.f, den2), inv3 = __fdividef(1.f, den3);
  for (int i = i0; i < i1; ++i) {
    int s = el[i];
    float4 sv = *(const float4*)(sd + (size_t)s * 4);
    float l0 = sv.x + d0; l0 = fminf(fmaxf(l0, 0.2f * l0), 60.f);
    float l1 = sv.y + d1; l1 = fminf(fmaxf(l1, 0.2f * l1), 60.f);
    float l2 = sv.z + d2; l2 = fminf(fmaxf(l2, 0.2f * l2), 60.f);
    float l3 = sv.w + d3; l3 = fminf(fmaxf(l3, 0.2f * l3), 60.f);
    __half2* wp = (__half2*)(w + (size_t)i * 4);
    wp[0] = __floats2half2_rn(__expf(l0) * inv0, __expf(l1) * inv1);
    wp[1] = __floats2half2_rn(__expf(l2) * inv2, __expf(l3) * inv3);
  }
}

// ==== FUSED edge attention, precomputed-alpha variant (pure gather-FMA) ==
struct EdgeOpP {
  const int* offs; const int* elist; const __half* al;
  const float* hsrc; float* out;
};

DEVI void csr_att_pre(const EdgeOpP& op, int dst, int lane)
{
  const int i0 = op.offs[dst], i1 = op.offs[dst + 1];
  const int hB = lane >> 4;
  const float* hsrc = op.hsrc;
  const int* el = op.elist;
  const __half* al = op.al;
  float a0 = 0.f, a1 = 0.f;
  int i = i0;
  for (; i + 4 <= i1; i += 4) {
    int s0 = el[i], s1 = el[i + 1], s2 = el[i + 2], s3 = el[i + 3];
    float w0 = __half2float(al[(size_t)i * 4 + hB]);
    float w1 = __half2float(al[(size_t)(i + 1) * 4 + hB]);
    float w2 = __half2float(al[(size_t)(i + 2) * 4 + hB]);
    float w3 = __half2float(al[(size_t)(i + 3) * 4 + hB]);
    float2 h0 = *(const float2*)(hsrc + (size_t)s0 * HIDn + lane * 2);
    float2 h1 = *(const float2*)(hsrc + (size_t)s1 * HIDn + lane * 2);
    float2 h2 = *(const float2*)(hsrc + (size_t)s2 * HIDn + lane * 2);
    float2 h3 = *(const float2*)(hsrc + (size_t)s3 * HIDn + lane * 2);
    a0 += h0.x * w0 + h1.x * w1 + h2.x * w2 + h3.x * w3;
    a1 += h0.y * w0 + h1.y * w1 + h2.y * w2 + h3.y * w3;
  }
  for (; i < i1; ++i) {
    int s = el[i];
    float w = __half2float(al[(size_t)i * 4 + hB]);
    float2 hv = *(const float2*)(hsrc + (size_t)s * HIDn + lane * 2);
    a0 += hv.x * w;
    a1 += hv.y * w;
  }
  float2 o2;
  o2.x = fmaxf(a0, 0.f);
  o2.y = fmaxf(a1, 0.f);
  *(float2*)(op.out + (size_t)dst * HIDn + lane * 2) = o2;
}

__global__ __launch_bounds__(256)
void csr_att3_pre(EdgeOpP op0, EdgeOpP op1, EdgeOpP op2, int Ndst)
{
  int wave = (blockIdx.x * 256 + threadIdx.x) >> 6;
  if (wave >= Ndst) return;
  const int lane = threadIdx.x & 63;
  if (blockIdx.y == 0)      csr_att_pre(op0, wave, lane);
  else if (blockIdx.y == 1) csr_att_pre(op1, wave, lane);
  else                      csr_att_pre(op2, wave, lane);
}

// ==== inline-weights variant (tier 2) =====================================
struct EdgeOp {
  const int* offs; const int* elist;
  const float* sdot; const float* ddot;
  const float* hsrc; float* out;
};

DEVI void csr_att_body(const EdgeOp& op, int dst, int lane)
{
  const int i0 = op.offs[dst], i1 = op.offs[dst + 1];
  const int hB = lane >> 4;
  const float ddB = op.ddot[dst * 4 + hB];
  const float* hsrc = op.hsrc;
  const float* sdot = op.sdot;
  const int* el = op.elist;
  float den = 0.f, a0 = 0.f, a1 = 0.f;
  int i = i0;
  for (; i + 4 <= i1; i += 4) {
    int s0 = el[i], s1 = el[i + 1], s2 = el[i + 2], s3 = el[i + 3];
    float2 h0 = *(const float2*)(hsrc + (size_t)s0 * HIDn + lane * 2);
    float2 h1 = *(const float2*)(hsrc + (size_t)s1 * HIDn + lane * 2);
    float2 h2 = *(const float2*)(hsrc + (size_t)s2 * HIDn + lane * 2);
    float2 h3 = *(const float2*)(hsrc + (size_t)s3 * HIDn + lane * 2);
    float l0 = sdot[s0 * 4 + hB] + ddB; l0 = fminf(fmaxf(l0, 0.2f * l0), 80.f);
    float l1 = sdot[s1 * 4 + hB] + ddB; l1 = fminf(fmaxf(l1, 0.2f * l1), 80.f);
    float l2 = sdot[s2 * 4 + hB] + ddB; l2 = fminf(fmaxf(l2, 0.2f * l2), 80.f);
    float l3 = sdot[s3 * 4 + hB] + ddB; l3 = fminf(fmaxf(l3, 0.2f * l3), 80.f);
    float e0 = __expf(l0), e1 = __expf(l1), e2 = __expf(l2), e3 = __expf(l3);
    den += (e0 + e1) + (e2 + e3);
    a0 += h0.x * e0 + h1.x * e1 + h2.x * e2 + h3.x * e3;
    a1 += h0.y * e0 + h1.y * e1 + h2.y * e2 + h3.y * e3;
  }
  for (; i < i1; ++i) {
    int s = el[i];
    float2 hv = *(const float2*)(hsrc + (size_t)s * HIDn + lane * 2);
    float lv = sdot[s * 4 + hB] + ddB; lv = fminf(fmaxf(lv, 0.2f * lv), 80.f);
    float e = __expf(lv);
    den += e;
    a0 += hv.x * e;
    a1 += hv.y * e;
  }
  float dinv = __fdividef(1.f, den + 1e-16f);
  float2 o2;
  o2.x = fmaxf(a0 * dinv, 0.f);
  o2.y = fmaxf(a1 * dinv, 0.f);
  *(float2*)(op.out + (size_t)dst * HIDn + lane * 2) = o2;
}

__global__ __launch_bounds__(256)
void csr_att3(EdgeOp op0, EdgeOp op1, EdgeOp op2, int Ndst)
{
  int wave = (blockIdx.x * 256 + threadIdx.x) >> 6;
  if (wave >= Ndst) return;
  const int lane = threadIdx.x & 63;
  if (blockIdx.y == 0)      csr_att_body(op0, wave, lane);
  else if (blockIdx.y == 1) csr_att_body(op1, wave, lane);
  else                      csr_att_body(op2, wave, lane);
}

// ---- fallback path (atomic scatter), tier 3 ------------------------------
__global__ void edge_logit_max(const int* __restrict__ ei,
                               const float* __restrict__ sdot,
                               const float* __restrict__ ddot,
                               unsigned* __restrict__ m)
{
  int e = blockIdx.x * blockDim.x + threadIdx.x;
  if (e >= En) return;
  int s = ei[e], d = ei[En + e];
  #pragma unroll
  for (int hh = 0; hh < 4; ++hh) {
    float l = sdot[s * 4 + hh] + ddot[d * 4 + hh];
    l = (l > 0.f) ? l : 0.2f * l;
    atomicMax(&m[d * 4 + hh], fmap(l));
  }
}

__global__ void edge_exp_sum(const int* __restrict__ ei,
                             const float* __restrict__ sdot,
                             const float* __restrict__ ddot,
                             const unsigned* __restrict__ m,
                             float* __restrict__ sden,
                             float* __restrict__ ebuf)
{
  int e = blockIdx.x * blockDim.x + threadIdx.x;
  if (e >= En) return;
  int s = ei[e], d = ei[En + e];
  #pragma unroll
  for (int hh = 0; hh < 4; ++hh) {
    float l = sdot[s * 4 + hh] + ddot[d * 4 + hh];
    l = (l > 0.f) ? l : 0.2f * l;
    float ex = expf(fminf(l - fdecode(m[d * 4 + hh]), 0.f));
    ebuf[e * 4 + hh] = ex;
    atomicAdd(&sden[d * 4 + hh], ex);
  }
}

__global__ __launch_bounds__(256)
void edge_scatter(const int* __restrict__ ei, const float* __restrict__ hsrc,
                  const float* __restrict__ ebuf, const float* __restrict__ sden,
                  float* __restrict__ out)
{
  int gid  = blockIdx.x * 256 + threadIdx.x;
  int e    = gid >> 6;
  if (e >= En) return;
  int lane = gid & 63;
  int s = ei[e], d = ei[En + e];
  #pragma unroll
  for (int half = 0; half < 2; ++half) {
    int c  = lane + half * 64;
    int hh = c >> 5;
    float alpha = ebuf[e * 4 + hh] / (sden[d * 4 + hh] + 1e-16f);
    atomicAdd(&out[(size_t)d * HIDn + c], hsrc[(size_t)s * HIDn + c] * alpha);
  }
}

__global__ void relu_k(float* __restrict__ x, int n)
{
  int i = blockIdx.x * blockDim.x + threadIdx.x;
  if (i < n) x[i] = fmaxf(x[i], 0.f);
}

// ---- semantic-attention score, 128x64 tile, 8x4 acc ---------------------
// grid (ceil(N/128), 2 col-halves, 2 inputs)
__global__ __launch_bounds__(256)
void score_gemm(const float* __restrict__ oA, const float* __restrict__ oB,
                const float* __restrict__ kW, const float* __restrict__ kb,
                const float* __restrict__ q, int N, float* __restrict__ slots)
{
  __shared__ float At[32][132];
  __shared__ float Ws[32][68];
  __shared__ float partw[4];
  const float* o = blockIdx.z ? oB : oA;
  const int row0 = blockIdx.x * 128;
  const int col0 = blockIdx.y * 64;
  const int tid  = threadIdx.x;
  const int r0 = (tid >> 4) << 3;
  const int c0 = (tid & 15) << 2;
  float acc[8][4] = {};

  for (int k0 = 0; k0 < 128; k0 += 32) {
    {
      const int r  = tid >> 1;
      const int kq = (tid & 1) << 4;
      const int row = row0 + r;
      float tmp[16];
      if (row < N) {
        loadrow8<0>(tmp,     o, nullptr, 0.f, 0.f, (size_t)row * HIDn + k0 + kq);
        loadrow8<0>(tmp + 8, o, nullptr, 0.f, 0.f, (size_t)row * HIDn + k0 + kq + 8);
      } else {
        #pragma unroll
        for (int i = 0; i < 16; ++i) tmp[i] = 0.f;
      }
      #pragma unroll
      for (int i = 0; i < 16; ++i) At[kq + i][r] = tmp[i];
    }
    {
      const int k  = tid >> 3;
      const int cq = (tid & 7) << 3;
      const float* wp = kW + (size_t)(k0 + k) * HIDn + col0 + cq;
      *(float4*)&Ws[k][cq]     = *(const float4*)wp;
      *(float4*)&Ws[k][cq + 4] = *(const float4*)(wp + 4);
    }
    __syncthreads();
    #pragma unroll
    for (int k = 0; k < 32; ++k) {
      float4 a0v = *(const float4*)&At[k][r0];
      float4 a1v = *(const float4*)&At[k][r0 + 4];
      float4 wv4 = *(const float4*)&Ws[k][c0];
      float av[8] = {a0v.x, a0v.y, a0v.z, a0v.w, a1v.x, a1v.y, a1v.z, a1v.w};
      float wq[4] = {wv4.x, wv4.y, wv4.z, wv4.w};
      #pragma unroll
      for (int i = 0; i < 8; ++i) {
        #pragma unroll
        for (int j = 0; j < 4; ++j) acc[i][j] += av[i] * wq[j];
      }
    }
    __syncthreads();
  }

  float sum = 0.f;
  #pragma unroll
  for (int i = 0; i < 8; ++i) {
    int row = row0 + r0 + i;
    if (row >= N) continue;
    #pragma unroll
    for (int j = 0; j < 4; ++j) {
      int col = col0 + c0 + j;
      sum += q[col] * tanh_fast(acc[i][j] + kb[col]);
    }
  }
  #pragma unroll
  for (int off = 32; off > 0; off >>= 1) sum += __shfl_down(sum, off);
  int wid = tid >> 6, lane = tid & 63;
  if (lane == 0) partw[wid] = sum;
  __syncthreads();
  if (tid == 0)
    atomicAdd(&slots[blockIdx.z],
              (partw[0] + partw[1] + partw[2] + partw[3]) * (1.f / (float)N));
}

__global__ void softmax2_kernel(float* sb)   // sb[0],sb[1] -> weights sb[2],sb[3]
{
  float s0 = sb[0], s1 = sb[1];
  float mx = fmaxf(s0, s1);
  float e0 = expf(s0 - mx), e1 = expf(s1 - mx);
  float inv = 1.f / (e0 + e1);
  sb[2] = e0 * inv;
  sb[3] = e1 * inv;
}

// ---- final projection, 128x64 tile, 8x4 acc, fused transform ------------
template<int MODE, bool NORM>
__global__ __launch_bounds__(256)
void proj_gemm(const float* __restrict__ fa, const float* __restrict__ fb,
               const float* __restrict__ wv,
               const float* __restrict__ pW, const float* __restrict__ pb,
               float* __restrict__ out, int N)
{
  __shared__ float At[32][132];
  __shared__ float Ws[32][68];
  float w2 = 0.f, w3 = 0.f;
  if (MODE == 2) { w2 = wv[2]; w3 = wv[3]; }
  const int row0 = blockIdx.x * 128;
  const int tid  = threadIdx.x;
  const int r0 = (tid >> 4) << 3;
  const int c0 = (tid & 15) << 2;     // 64 cols
  float acc[8][4] = {};

  for (int k0 = 0; k0 < 128; k0 += 32) {
    {
      const int r  = tid >> 1;
      const int kq = (tid & 1) << 4;
      const int row = row0 + r;
      float tmp[16];
      if (row < N) {
        loadrow8<MODE>(tmp,     fa, fb, w2, w3, (size_t)row * HIDn + k0 + kq);
        loadrow8<MODE>(tmp + 8, fa, fb, w2, w3, (size_t)row * HIDn + k0 + kq + 8);
      } else {
        #pragma unroll
        for (int i = 0; i < 16; ++i) tmp[i] = 0.f;
      }
      #pragma unroll
      for (int i = 0; i < 16; ++i) At[kq + i][r] = tmp[i];
    }
    {
      const int k  = tid >> 3;
      const int cq = (tid & 7) << 3;
      const float* wp = pW + (size_t)(k0 + k) * OUTn + cq;
      *(float4*)&Ws[k][cq]     = *(const float4*)wp;
      *(float4*)&Ws[k][cq + 4] = *(const float4*)(wp + 4);
    }
    __syncthreads();
    #pragma unroll
    for (int k = 0; k < 32; ++k) {
      float4 a0v = *(const float4*)&At[k][r0];
      float4 a1v = *(const float4*)&At[k][r0 + 4];
      float4 wv4 = *(const float4*)&Ws[k][c0];
      float av[8] = {a0v.x, a0v.y, a0v.z, a0v.w, a1v.x, a1v.y, a1v.z, a1v.w};
      float wq[4] = {wv4.x, wv4.y, wv4.z, wv4.w};
      #pragma unroll
      for (int i = 0; i < 8; ++i) {
        #pragma unroll
        for (int j = 0; j < 4; ++j) acc[i][j] += av[i] * wq[j];
      }
    }
    __syncthreads();
  }

  float a[8][4];
  #pragma unroll
  for (int i = 0; i < 8; ++i)
    #pragma unroll
    for (int j = 0; j < 4; ++j) a[i][j] = acc[i][j] + pb[c0 + j];

  if (NORM) {
    #pragma unroll
    for (int i = 0; i < 8; ++i) {
      float ss = a[i][0]*a[i][0] + a[i][1]*a[i][1] + a[i][2]*a[i][2] + a[i][3]*a[i][3];
      #pragma unroll
      for (int off = 1; off < 16; off <<= 1) ss += __shfl_xor(ss, off);
      float inv = 1.f / fmaxf(sqrtf(ss), 1e-12f);
      #pragma unroll
      for (int j = 0; j < 4; ++j) a[i][j] *= inv;
    }
  }

  #pragma unroll
  for (int i = 0; i < 8; ++i) {
    int row = row0 + r0 + i;
    if (row >= N) continue;
    #pragma unroll
    for (int j = 0; j < 4; ++j)
      out[(size_t)row * OUTn + c0 + j] = a[i][j];
  }
}

// ---- fallback edge-op dispatcher (tier 3) -------------------------------
static void run_edge_fb(hipStream_t stream, const int* ei,
                        const float* sdot, const float* ddot, const float* hsrc,
                        float* outb, int Ndst,
                        unsigned* mbuf, float* sden, float* ebuf)
{
  hipMemsetAsync(mbuf, 0, (size_t)Ndst * 4 * sizeof(unsigned), stream);
  edge_logit_max<<<(En + 255) / 256, 256, 0, stream>>>(ei, sdot, ddot, mbuf);
  hipMemsetAsync(sden, 0, (size_t)Ndst * 4 * sizeof(float), stream);
  edge_exp_sum<<<(En + 255) / 256, 256, 0, stream>>>(ei, sdot, ddot, mbuf, sden, ebuf);
  hipMemsetAsync(outb, 0, (size_t)Ndst * HIDn * sizeof(float), stream);
  edge_scatter<<<((size_t)En * 64 + 255) / 256, 256, 0, stream>>>(ei, hsrc, ebuf, sden, outb);
  relu_k<<<((size_t)Ndst * HIDn + 255) / 256, 256, 0, stream>>>(outb, Ndst * HIDn);
}

extern "C" void kernel_launch(void* const* d_in, const int* in_sizes, int n_in,
                              void* d_out, int out_size, void* d_ws, size_t ws_size,
                              hipStream_t stream)
{
  const float* xc    = (const float*)d_in[0];
  const float* xd    = (const float*)d_in[1];
  const int*   ei_cc = (const int*)d_in[2];
  const int*   ei_dc = (const int*)d_in[3];
  const int*   ei_cd = (const int*)d_in[4];
  const float* W1c = (const float*)d_in[5];  const float* b1c = (const float*)d_in[6];
  const float* W1d = (const float*)d_in[7];  const float* b1d = (const float*)d_in[8];
  const float* a1s_cc = (const float*)d_in[9];  const float* a1d_cc = (const float*)d_in[10];
  const float* a1s_dc = (const float*)d_in[11]; const float* a1d_dc = (const float*)d_in[12];
  const float* a1s_cd = (const float*)d_in[13]; const float* a1d_cd = (const float*)d_in[14];
  const float* k1W = (const float*)d_in[15]; const float* k1b = (const float*)d_in[16];
  const float* q1  = (const float*)d_in[17];
  const float* W2c = (const float*)d_in[18]; const float* b2c = (const float*)d_in[19];
  const float* W2d = (const float*)d_in[20]; const float* b2d = (const float*)d_in[21];
  const float* a2s_cc = (const float*)d_in[22]; const float* a2d_cc = (const float*)d_in[23];
  const float* a2s_dc = (const float*)d_in[24]; const float* a2d_dc = (const float*)d_in[25];
  const float* a2s_cd = (const float*)d_in[26]; const float* a2d_cd = (const float*)d_in[27];
  const float* k2W = (const float*)d_in[28]; const float* k2b = (const float*)d_in[29];
  const float* q2  = (const float*)d_in[30];
  const float* pW  = (const float*)d_in[31]; const float* pb  = (const float*)d_in[32];

  // ---------------- workspace layout (fp32) ----------------
  float* ws = (float*)d_ws;
  const size_t NB = (size_t)NCn * HIDn;           // 6,400,000 floats per node buffer
  float* B0 = ws;
  float* B1 = ws + NB;
  float* B2 = ws + 2 * NB;
  float* B3 = ws + 3 * NB;
  float* B4 = ws + 4 * NB;
  float* sml = ws + 5 * NB;
  // six dot arrays (N*4 each)
  float* scc = sml;
  float* dcc = sml + 200000;
  float* ddc = sml + 400000;
  float* scd = sml + 600000;
  float* sdc = sml + 800000;
  float* dcd = sml + 1000000;
  float* scoreB = sml + 1200000;                 // [s0,s1,w0,w1, s0',s1',w0',w1']
  float* R0 = sml + 1200016;                     // CSR region (or fallback temps)
  // CSR sub-layout: offs 150,012 ints | elist 1,200,000 ints | tmp 150,000 ints | wcsr 4,800,000 halves
  int*  R0i = (int*)R0;
  int*    offsBase  = R0i;
  int*    elistBase = R0i + 150012;
  int*    tmpBase   = R0i + 1350012;
  __half* wcsrBase  = (__half*)(R0i + 1500012);
  // fallback temps overlay
  unsigned* mbuf = (unsigned*)R0;                // N*4
  float*    sden = R0 + 200000;                  // N*4
  float*    ebuf = R0 + 400000;                  // E*4

  const size_t REQ1 = 5 * NB + 1200016 + 1500012 + 2400000;   // 37,100,028 fl = 148.4 MB
  const size_t REQ2 = 5 * NB + 1200016 + 1500012;             // 34,700,028 fl = 138.8 MB
  const bool tier1 = ws_size >= REQ1 * sizeof(float);
  const bool tier2 = !tier1 && ws_size >= REQ2 * sizeof(float);
  const bool useCsr = tier1 || tier2;

  if (useCsr) {
    hipMemsetAsync(tmpBase, 0, 150000 * sizeof(int), stream);
    hist3<<<(3 * En + 255) / 256, 256, 0, stream>>>(ei_cc, ei_dc, ei_cd, tmpBase);
    scan3<<<3, 1024, 0, stream>>>(tmpBase, offsBase);
    hipMemsetAsync(tmpBase, 0, 150000 * sizeof(int), stream);
    fill3<<<(3 * En + 255) / 256, 256, 0, stream>>>(ei_cc, ei_dc, ei_cd,
                                                    offsBase, tmpBase, elistBase);
  }

  hipMemsetAsync(scoreB, 0, 8 * sizeof(float), stream);

  const int NT128 = (NCn + 127) / 128;
  const dim3 gemmGrid(NT128, HIDn / 64);
  const int dotGrid = (NCn * 4 + 255) / 256;
  const int* offs0 = offsBase;
  const int* offs1 = offsBase + 50004;
  const int* offs2 = offsBase + 100008;
  const int* el0 = elistBase;
  const int* el1 = elistBase + En;
  const int* el2 = elistBase + 2 * (size_t)En;
  __half* wc0 = wcsrBase;
  __half* wc1 = wcsrBase + (size_t)En * 4;
  __half* wc2 = wcsrBase + (size_t)En * 8;

  // per-layer edge-attention dispatcher
  auto edge_layer = [&](float* hc, float* hd, float* oCC, float* oDC, float* oCD) {
    if (tier1) {
      edge_w3<<<(150000 + 255) / 256, 256, 0, stream>>>(offsBase, elistBase,
                                                        scc, dcc, sdc, ddc, scd, dcd, wcsrBase);
      EdgeOpP p0{offs0, el0, wc0, hc, oCC};
      EdgeOpP p1{offs1, el1, wc1, hd, oDC};
      EdgeOpP p2{offs2, el2, wc2, hc, oCD};
      csr_att3_pre<<<dim3((NCn + 3) / 4, 3), 256, 0, stream>>>(p0, p1, p2, NCn);
    } else if (tier2) {
      EdgeOp o0{offs0, el0, scc, dcc, hc, oCC};
      EdgeOp o1{offs1, el1, sdc, ddc, hd, oDC};
      EdgeOp o2{offs2, el2, scd, dcd, hc, oCD};
      csr_att3<<<dim3((NCn + 3) / 4, 3), 256, 0, stream>>>(o0, o1, o2, NCn);
    } else {
      run_edge_fb(stream, ei_cc, scc, dcc, hc, oCC, NCn, mbuf, sden, ebuf);
      run_edge_fb(stream, ei_dc, sdc, ddc, hd, oDC, NCn, mbuf, sden, ebuf);
      run_edge_fb(stream, ei_cd, scd, dcd, hc, oCD, NDn, mbuf, sden, ebuf);
    }
  };

  // ---------------- layer 1 ----------------
  gemm_bias<256, 0><<<gemmGrid, 256, 0, stream>>>(xc, nullptr, nullptr, W1c, b1c, B0, NCn, HIDn);
  gemm_bias<256, 0><<<gemmGrid, 256, 0, stream>>>(xd, nullptr, nullptr, W1d, b1d, B1, NDn, HIDn);

  dot6<<<dotGrid, 256, 0, stream>>>(B0, B1, a1s_cc, a1d_cc, a1s_dc, a1d_dc, a1s_cd, a1d_cd,
                                    scc, dcc, ddc, scd, sdc, dcd, NCn);
  edge_layer(B0, B1, B2, B3, B4);

  score_gemm<<<dim3(NT128, 2, 2), 256, 0, stream>>>(B2, B3, k1W, k1b, q1, NCn, scoreB);
  softmax2_kernel<<<1, 1, 0, stream>>>(scoreB);

  // ---------------- layer 2 (combine/elu fused into A-loads) ----------------
  gemm_bias<128, 2><<<gemmGrid, 256, 0, stream>>>(B2, B3, scoreB, W2c, b2c, B0, NCn, HIDn);
  gemm_bias<128, 1><<<gemmGrid, 256, 0, stream>>>(B4, nullptr, nullptr, W2d, b2d, B1, NDn, HIDn);

  dot6<<<dotGrid, 256, 0, stream>>>(B0, B1, a2s_cc, a2d_cc, a2s_dc, a2d_dc, a2s_cd, a2d_cd,
                                    scc, dcc, ddc, scd, sdc, dcd, NCn);
  edge_layer(B0, B1, B2, B3, B4);

  score_gemm<<<dim3(NT128, 2, 2), 256, 0, stream>>>(B2, B3, k2W, k2b, q2, NCn, scoreB + 4);
  softmax2_kernel<<<1, 1, 0, stream>>>(scoreB + 4);

  // ---------------- projection (+combine/elu fused) ----------------
  proj_gemm<2, true ><<<NT128, 256, 0, stream>>>(B2, B3, scoreB + 4, pW, pb, (float*)d_out, NCn);
  proj_gemm<1, false><<<NT128, 256, 0, stream>>>(B4, nullptr, nullptr, pW, pb,
                                                 (float*)d_out + (size_t)NCn * OUTn, NDn);
}

// Round 12
// 682.528 us; speedup vs baseline: 1.2735x; 1.1766x over previous
//
#include <hip/hip_runtime.h>
#include <hip/hip_fp16.h>
#include <cmath>

#define DEVI static __device__ __forceinline__

constexpr int HIDn = 128, OUTn = 64;
constexpr int NCn = 50000, NDn = 50000, En = 400000;

// monotonic float->uint mapping for atomicMax on floats (handles signs)
DEVI unsigned fmap(float f) {
  int i = __float_as_int(f);
  return (i < 0) ? ~((unsigned)i) : (((unsigned)i) | 0x80000000u);
}
DEVI float fdecode(unsigned u) {
  int i = (u & 0x80000000u) ? (int)(u & 0x7fffffffu) : (int)(~u);
  return __int_as_float(i);
}

DEVI float tanh_fast(float x) {           // 1 - 2/(e^{2x}+1); saturates correctly
  float e = __expf(2.f * x);
  return 1.f - __fdividef(2.f, e + 1.f);
}

// ---- vectorized 8-wide A-row load + fused transform (value-based) -------
// MODE: 0=plain, 1=elu(x), 2=elu(w2*a+w3*b).  base must be 16B-aligned.
template<int MODE>
DEVI void loadrow8(float* __restrict__ tmp,
                   const float* __restrict__ A, const float* __restrict__ A2,
                   float w2, float w3, size_t base)
{
  const float4* p = (const float4*)(A + base);
  float4 u0 = p[0], u1 = p[1];
  float v[8] = {u0.x, u0.y, u0.z, u0.w, u1.x, u1.y, u1.z, u1.w};
  if (MODE == 2) {
    const float4* q = (const float4*)(A2 + base);
    float4 t0 = q[0], t1 = q[1];
    float vb[8] = {t0.x, t0.y, t0.z, t0.w, t1.x, t1.y, t1.z, t1.w};
    #pragma unroll
    for (int i = 0; i < 8; ++i) v[i] = w2 * v[i] + w3 * vb[i];
  }
  if (MODE >= 1) {
    #pragma unroll
    for (int i = 0; i < 8; ++i) v[i] = (v[i] > 0.f) ? v[i] : (__expf(v[i]) - 1.f);
  }
  #pragma unroll
  for (int i = 0; i < 8; ++i) tmp[i] = v[i];
}

// ------- GEMM: C[N,KO] = xform(A)[N,KI] @ W[KI,KO] + b; 128x64 tile ------
// 256 threads, 8x4 acc/thread. grid = (ceil(N/128), KO/64).
// OUT16: write C as __half (for gather-consumed h buffers).
template<int KI, int MODE, int OUT16>
__global__ __launch_bounds__(256)
void gemm_bias(const float* __restrict__ A, const float* __restrict__ A2,
               const float* __restrict__ wv,
               const float* __restrict__ W, const float* __restrict__ b,
               void* __restrict__ Cv, int N, int KO)
{
  __shared__ float At[32][132];   // A^T chunk: [k][row], 128 rows
  __shared__ float Ws[32][68];    // W chunk:   [k][col], 64 cols
  float w2 = 0.f, w3 = 0.f;
  if (MODE == 2) { w2 = wv[2]; w3 = wv[3]; }
  const int row0 = blockIdx.x * 128;
  const int col0 = blockIdx.y * 64;
  const int tid  = threadIdx.x;
  const int r0 = (tid >> 4) << 3;     // 0..120 step 8
  const int c0 = (tid & 15) << 2;     // 0..60  step 4
  float acc[8][4] = {};

  for (int k0 = 0; k0 < KI; k0 += 32) {
    {
      const int r  = tid >> 1;
      const int kq = (tid & 1) << 4;
      const int row = row0 + r;
      float tmp[16];
      if (row < N) {
        loadrow8<MODE>(tmp,     A, A2, w2, w3, (size_t)row * KI + k0 + kq);
        loadrow8<MODE>(tmp + 8, A, A2, w2, w3, (size_t)row * KI + k0 + kq + 8);
      } else {
        #pragma unroll
        for (int i = 0; i < 16; ++i) tmp[i] = 0.f;
      }
      #pragma unroll
      for (int i = 0; i < 16; ++i) At[kq + i][r] = tmp[i];
    }
    {
      const int k  = tid >> 3;
      const int cq = (tid & 7) << 3;
      const float* wp = W + (size_t)(k0 + k) * KO + col0 + cq;
      *(float4*)&Ws[k][cq]     = *(const float4*)wp;
      *(float4*)&Ws[k][cq + 4] = *(const float4*)(wp + 4);
    }
    __syncthreads();
    #pragma unroll
    for (int k = 0; k < 32; ++k) {
      float4 a0v = *(const float4*)&At[k][r0];
      float4 a1v = *(const float4*)&At[k][r0 + 4];
      float4 wv4 = *(const float4*)&Ws[k][c0];
      float av[8] = {a0v.x, a0v.y, a0v.z, a0v.w, a1v.x, a1v.y, a1v.z, a1v.w};
      float wq[4] = {wv4.x, wv4.y, wv4.z, wv4.w};
      #pragma unroll
      for (int i = 0; i < 8; ++i) {
        #pragma unroll
        for (int j = 0; j < 4; ++j) acc[i][j] += av[i] * wq[j];
      }
    }
    __syncthreads();
  }

  #pragma unroll
  for (int i = 0; i < 8; ++i) {
    const int row = row0 + r0 + i;
    if (row >= N) continue;
    float v0 = acc[i][0] + b[col0 + c0 + 0];
    float v1 = acc[i][1] + b[col0 + c0 + 1];
    float v2 = acc[i][2] + b[col0 + c0 + 2];
    float v3 = acc[i][3] + b[col0 + c0 + 3];
    if (OUT16) {
      __half* C = (__half*)Cv;
      __half2* cp = (__half2*)(C + (size_t)row * KO + col0 + c0);
      cp[0] = __floats2half2_rn(v0, v1);
      cp[1] = __floats2half2_rn(v2, v3);
    } else {
      float* C = (float*)Cv;
      float* cp = C + (size_t)row * KO + col0 + c0;
      cp[0] = v0; cp[1] = v1; cp[2] = v2; cp[3] = v3;
    }
  }
}

// ---- all six per-(node,head) attention dots of one layer in one pass ----
DEVI float dot4f(float4 a, float4 b) { return a.x*b.x + a.y*b.y + a.z*b.z + a.w*b.w; }

template<int HALF>
DEVI void loadrow32h(const void* base, size_t off, float* v)
{
  if (HALF) {
    const __half* p = (const __half*)base + off;
    #pragma unroll
    for (int i = 0; i < 4; ++i) {
      float4 raw = *(const float4*)(p + i * 8);     // 8 halves
      const __half2* h2 = (const __half2*)&raw;
      #pragma unroll
      for (int j = 0; j < 4; ++j) {
        float2 f = __half22float2(h2[j]);
        v[i * 8 + j * 2]     = f.x;
        v[i * 8 + j * 2 + 1] = f.y;
      }
    }
  } else {
    const float* p = (const float*)base + off;
    #pragma unroll
    for (int i = 0; i < 8; ++i) {
      float4 u = *(const float4*)(p + i * 4);
      v[i * 4] = u.x; v[i * 4 + 1] = u.y; v[i * 4 + 2] = u.z; v[i * 4 + 3] = u.w;
    }
  }
}

template<int HALF>
__global__ void dot6(const void* __restrict__ hc, const void* __restrict__ hd,
                     const float* __restrict__ ascc, const float* __restrict__ adcc,
                     const float* __restrict__ asdc, const float* __restrict__ addc,
                     const float* __restrict__ ascd, const float* __restrict__ adcd,
                     float* __restrict__ scc, float* __restrict__ dcc,
                     float* __restrict__ ddc, float* __restrict__ scd,
                     float* __restrict__ sdc, float* __restrict__ dcd, int N)
{
  int idx = blockIdx.x * blockDim.x + threadIdx.x;
  if (idx >= N * 4) return;
  int n = idx >> 2, hh = idx & 3;
  float hv[32], dv[32];
  loadrow32h<HALF>(hc, (size_t)n * HIDn + hh * 32, hv);
  loadrow32h<HALF>(hd, (size_t)n * HIDn + hh * 32, dv);
  const float4* a1 = (const float4*)(ascc + hh * 32);
  const float4* a2 = (const float4*)(adcc + hh * 32);
  const float4* a3 = (const float4*)(addc + hh * 32);
  const float4* a4 = (const float4*)(ascd + hh * 32);
  const float4* a5 = (const float4*)(asdc + hh * 32);
  const float4* a6 = (const float4*)(adcd + hh * 32);
  float s1 = 0, s2 = 0, s3 = 0, s4 = 0, t1 = 0, t2 = 0;
  #pragma unroll
  for (int i = 0; i < 8; ++i) {
    float4 hq = make_float4(hv[i*4], hv[i*4+1], hv[i*4+2], hv[i*4+3]);
    s1 += dot4f(hq, a1[i]);
    s2 += dot4f(hq, a2[i]);
    s3 += dot4f(hq, a3[i]);
    s4 += dot4f(hq, a4[i]);
    float4 dq = make_float4(dv[i*4], dv[i*4+1], dv[i*4+2], dv[i*4+3]);
    t1 += dot4f(dq, a5[i]);
    t2 += dot4f(dq, a6[i]);
  }
  scc[idx] = s1; dcc[idx] = s2; ddc[idx] = s3;
  scd[idx] = s4; sdc[idx] = t1; dcd[idx] = t2;
}

// ================= CSR build, all 3 graphs batched =======================
__global__ void hist3(const int* __restrict__ ei0, const int* __restrict__ ei1,
                      const int* __restrict__ ei2, int* __restrict__ tmpBase)
{
  int gid = blockIdx.x * blockDim.x + threadIdx.x;
  if (gid >= 3 * En) return;
  int g = gid / En, e = gid - g * En;
  const int* ei = (g == 0) ? ei0 : (g == 1) ? ei1 : ei2;
  atomicAdd(&tmpBase[g * 50000 + ei[En + e]], 1);
}

// one block per graph (grid=3, block=1024)
__global__ void scan3(const int* __restrict__ tmpBase, int* __restrict__ offsBase)
{
  const int n = 50000;
  const int* deg = tmpBase + blockIdx.x * 50000;
  int* offs = offsBase + blockIdx.x * 50004;
  __shared__ int wsum[16];
  __shared__ int carry_sh;
  int tid = threadIdx.x;
  if (tid == 0) { carry_sh = 0; offs[0] = 0; }
  __syncthreads();
  const int nw = blockDim.x >> 6;
  int lane = tid & 63, w = tid >> 6;
  for (int base = 0; base < n; base += blockDim.x) {
    int i = base + tid;
    int v = (i < n) ? deg[i] : 0;
    int x = v;
    #pragma unroll
    for (int off = 1; off < 64; off <<= 1) {
      int y = __shfl_up(x, off);
      if (lane >= off) x += y;
    }
    if (lane == 63) wsum[w] = x;
    __syncthreads();
    if (tid == 0) {
      int s = carry_sh;
      for (int ww = 0; ww < nw; ++ww) { int t = wsum[ww]; wsum[ww] = s; s += t; }
      carry_sh = s;
    }
    __syncthreads();
    if (i < n) offs[i + 1] = wsum[w] + x;
    __syncthreads();
  }
}

__global__ void fill3(const int* __restrict__ ei0, const int* __restrict__ ei1,
                      const int* __restrict__ ei2, const int* __restrict__ offsBase,
                      int* __restrict__ cursorBase, int* __restrict__ elistBase)
{
  int gid = blockIdx.x * blockDim.x + threadIdx.x;
  if (gid >= 3 * En) return;
  int g = gid / En, e = gid - g * En;
  const int* ei = (g == 0) ? ei0 : (g == 1) ? ei1 : ei2;
  const int* offs = offsBase + g * 50004;
  int* cursor = cursorBase + g * 50000;
  int* elist = elistBase + (size_t)g * En;
  int s = ei[e], d = ei[En + e];
  int p = atomicAdd(&cursor[d], 1);
  elist[offs[d] + p] = s;
}

// ==== FUSED edge attention (CSR, inline weights, fp16 h gather) ==========
// out[dst] = relu( (sum_e e^{l_e} h16[e]) / (sum_e e^{l_e} + 1e-16) )
struct EdgeOp {
  const int* offs; const int* elist;
  const float* sdot; const float* ddot;
  const __half* hsrc; float* out;
};

DEVI void csr_att_body(const EdgeOp& op, int dst, int lane)
{
  const int i0 = op.offs[dst], i1 = op.offs[dst + 1];
  const int hB = lane >> 4;
  const float ddB = op.ddot[dst * 4 + hB];
  const __half* hsrc = op.hsrc;
  const float* sdot = op.sdot;
  const int* el = op.elist;
  float den = 0.f, a0 = 0.f, a1 = 0.f;
  int i = i0;
  for (; i + 4 <= i1; i += 4) {
    int s0 = el[i], s1 = el[i + 1], s2 = el[i + 2], s3 = el[i + 3];
    __half2 g0 = *(const __half2*)(hsrc + (size_t)s0 * HIDn + lane * 2);
    __half2 g1 = *(const __half2*)(hsrc + (size_t)s1 * HIDn + lane * 2);
    __half2 g2 = *(const __half2*)(hsrc + (size_t)s2 * HIDn + lane * 2);
    __half2 g3 = *(const __half2*)(hsrc + (size_t)s3 * HIDn + lane * 2);
    float l0 = sdot[s0 * 4 + hB] + ddB; l0 = fminf(fmaxf(l0, 0.2f * l0), 80.f);
    float l1 = sdot[s1 * 4 + hB] + ddB; l1 = fminf(fmaxf(l1, 0.2f * l1), 80.f);
    float l2 = sdot[s2 * 4 + hB] + ddB; l2 = fminf(fmaxf(l2, 0.2f * l2), 80.f);
    float l3 = sdot[s3 * 4 + hB] + ddB; l3 = fminf(fmaxf(l3, 0.2f * l3), 80.f);
    float e0 = __expf(l0), e1 = __expf(l1), e2 = __expf(l2), e3 = __expf(l3);
    den += (e0 + e1) + (e2 + e3);
    float2 h0 = __half22float2(g0), h1 = __half22float2(g1);
    float2 h2 = __half22float2(g2), h3 = __half22float2(g3);
    a0 += h0.x * e0 + h1.x * e1 + h2.x * e2 + h3.x * e3;
    a1 += h0.y * e0 + h1.y * e1 + h2.y * e2 + h3.y * e3;
  }
  for (; i < i1; ++i) {
    int s = el[i];
    float2 hv = __half22float2(*(const __half2*)(hsrc + (size_t)s * HIDn + lane * 2));
    float lv = sdot[s * 4 + hB] + ddB; lv = fminf(fmaxf(lv, 0.2f * lv), 80.f);
    float e = __expf(lv);
    den += e;
    a0 += hv.x * e;
    a1 += hv.y * e;
  }
  float dinv = __fdividef(1.f, den + 1e-16f);
  float2 o2;
  o2.x = fmaxf(a0 * dinv, 0.f);
  o2.y = fmaxf(a1 * dinv, 0.f);
  *(float2*)(op.out + (size_t)dst * HIDn + lane * 2) = o2;
}

__global__ __launch_bounds__(256)
void csr_att3(EdgeOp op0, EdgeOp op1, EdgeOp op2, int Ndst)
{
  int wave = (blockIdx.x * 256 + threadIdx.x) >> 6;
  if (wave >= Ndst) return;
  const int lane = threadIdx.x & 63;
  if (blockIdx.y == 0)      csr_att_body(op0, wave, lane);
  else if (blockIdx.y == 1) csr_att_body(op1, wave, lane);
  else                      csr_att_body(op2, wave, lane);
}

// ---- fallback path (atomic scatter, fp32 h), used only if ws too small --
__global__ void edge_logit_max(const int* __restrict__ ei,
                               const float* __restrict__ sdot,
                               const float* __restrict__ ddot,
                               unsigned* __restrict__ m)
{
  int e = blockIdx.x * blockDim.x + threadIdx.x;
  if (e >= En) return;
  int s = ei[e], d = ei[En + e];
  #pragma unroll
  for (int hh = 0; hh < 4; ++hh) {
    float l = sdot[s * 4 + hh] + ddot[d * 4 + hh];
    l = (l > 0.f) ? l : 0.2f * l;
    atomicMax(&m[d * 4 + hh], fmap(l));
  }
}

__global__ void edge_exp_sum(const int* __restrict__ ei,
                             const float* __restrict__ sdot,
                             const float* __restrict__ ddot,
                             const unsigned* __restrict__ m,
                             float* __restrict__ sden,
                             float* __restrict__ ebuf)
{
  int e = blockIdx.x * blockDim.x + threadIdx.x;
  if (e >= En) return;
  int s = ei[e], d = ei[En + e];
  #pragma unroll
  for (int hh = 0; hh < 4; ++hh) {
    float l = sdot[s * 4 + hh] + ddot[d * 4 + hh];
    l = (l > 0.f) ? l : 0.2f * l;
    float ex = expf(fminf(l - fdecode(m[d * 4 + hh]), 0.f));
    ebuf[e * 4 + hh] = ex;
    atomicAdd(&sden[d * 4 + hh], ex);
  }
}

__global__ __launch_bounds__(256)
void edge_scatter(const int* __restrict__ ei, const float* __restrict__ hsrc,
                  const float* __restrict__ ebuf, const float* __restrict__ sden,
                  float* __restrict__ out)
{
  int gid  = blockIdx.x * 256 + threadIdx.x;
  int e    = gid >> 6;
  if (e >= En) return;
  int lane = gid & 63;
  int s = ei[e], d = ei[En + e];
  #pragma unroll
  for (int half = 0; half < 2; ++half) {
    int c  = lane + half * 64;
    int hh = c >> 5;
    float alpha = ebuf[e * 4 + hh] / (sden[d * 4 + hh] + 1e-16f);
    atomicAdd(&out[(size_t)d * HIDn + c], hsrc[(size_t)s * HIDn + c] * alpha);
  }
}

__global__ void relu_k(float* __restrict__ x, int n)
{
  int i = blockIdx.x * blockDim.x + threadIdx.x;
  if (i < n) x[i] = fmaxf(x[i], 0.f);
}

// ---- semantic-attention score, 128x64 tile, 8x4 acc ---------------------
// grid (ceil(N/128), 2 col-halves, 2 inputs)
__global__ __launch_bounds__(256)
void score_gemm(const float* __restrict__ oA, const float* __restrict__ oB,
                const float* __restrict__ kW, const float* __restrict__ kb,
                const float* __restrict__ q, int N, float* __restrict__ slots)
{
  __shared__ float At[32][132];
  __shared__ float Ws[32][68];
  __shared__ float partw[4];
  const float* o = blockIdx.z ? oB : oA;
  const int row0 = blockIdx.x * 128;
  const int col0 = blockIdx.y * 64;
  const int tid  = threadIdx.x;
  const int r0 = (tid >> 4) << 3;
  const int c0 = (tid & 15) << 2;
  float acc[8][4] = {};

  for (int k0 = 0; k0 < 128; k0 += 32) {
    {
      const int r  = tid >> 1;
      const int kq = (tid & 1) << 4;
      const int row = row0 + r;
      float tmp[16];
      if (row < N) {
        loadrow8<0>(tmp,     o, nullptr, 0.f, 0.f, (size_t)row * HIDn + k0 + kq);
        loadrow8<0>(tmp + 8, o, nullptr, 0.f, 0.f, (size_t)row * HIDn + k0 + kq + 8);
      } else {
        #pragma unroll
        for (int i = 0; i < 16; ++i) tmp[i] = 0.f;
      }
      #pragma unroll
      for (int i = 0; i < 16; ++i) At[kq + i][r] = tmp[i];
    }
    {
      const int k  = tid >> 3;
      const int cq = (tid & 7) << 3;
      const float* wp = kW + (size_t)(k0 + k) * HIDn + col0 + cq;
      *(float4*)&Ws[k][cq]     = *(const float4*)wp;
      *(float4*)&Ws[k][cq + 4] = *(const float4*)(wp + 4);
    }
    __syncthreads();
    #pragma unroll
    for (int k = 0; k < 32; ++k) {
      float4 a0v = *(const float4*)&At[k][r0];
      float4 a1v = *(const float4*)&At[k][r0 + 4];
      float4 wv4 = *(const float4*)&Ws[k][c0];
      float av[8] = {a0v.x, a0v.y, a0v.z, a0v.w, a1v.x, a1v.y, a1v.z, a1v.w};
      float wq[4] = {wv4.x, wv4.y, wv4.z, wv4.w};
      #pragma unroll
      for (int i = 0; i < 8; ++i) {
        #pragma unroll
        for (int j = 0; j < 4; ++j) acc[i][j] += av[i] * wq[j];
      }
    }
    __syncthreads();
  }

  float sum = 0.f;
  #pragma unroll
  for (int i = 0; i < 8; ++i) {
    int row = row0 + r0 + i;
    if (row >= N) continue;
    #pragma unroll
    for (int j = 0; j < 4; ++j) {
      int col = col0 + c0 + j;
      sum += q[col] * tanh_fast(acc[i][j] + kb[col]);
    }
  }
  #pragma unroll
  for (int off = 32; off > 0; off >>= 1) sum += __shfl_down(sum, off);
  int wid = tid >> 6, lane = tid & 63;
  if (lane == 0) partw[wid] = sum;
  __syncthreads();
  if (tid == 0)
    atomicAdd(&slots[blockIdx.z],
              (partw[0] + partw[1] + partw[2] + partw[3]) * (1.f / (float)N));
}

__global__ void softmax2_kernel(float* sb)   // sb[0],sb[1] -> weights sb[2],sb[3]
{
  float s0 = sb[0], s1 = sb[1];
  float mx = fmaxf(s0, s1);
  float e0 = expf(s0 - mx), e1 = expf(s1 - mx);
  float inv = 1.f / (e0 + e1);
  sb[2] = e0 * inv;
  sb[3] = e1 * inv;
}

// ---- final projection, 128x64 tile, 8x4 acc, fused transform ------------
template<int MODE, bool NORM>
__global__ __launch_bounds__(256)
void proj_gemm(const float* __restrict__ fa, const float* __restrict__ fb,
               const float* __restrict__ wv,
               const float* __restrict__ pW, const float* __restrict__ pb,
               float* __restrict__ out, int N)
{
  __shared__ float At[32][132];
  __shared__ float Ws[32][68];
  float w2 = 0.f, w3 = 0.f;
  if (MODE == 2) { w2 = wv[2]; w3 = wv[3]; }
  const int row0 = blockIdx.x * 128;
  const int tid  = threadIdx.x;
  const int r0 = (tid >> 4) << 3;
  const int c0 = (tid & 15) << 2;     // 64 cols
  float acc[8][4] = {};

  for (int k0 = 0; k0 < 128; k0 += 32) {
    {
      const int r  = tid >> 1;
      const int kq = (tid & 1) << 4;
      const int row = row0 + r;
      float tmp[16];
      if (row < N) {
        loadrow8<MODE>(tmp,     fa, fb, w2, w3, (size_t)row * HIDn + k0 + kq);
        loadrow8<MODE>(tmp + 8, fa, fb, w2, w3, (size_t)row * HIDn + k0 + kq + 8);
      } else {
        #pragma unroll
        for (int i = 0; i < 16; ++i) tmp[i] = 0.f;
      }
      #pragma unroll
      for (int i = 0; i < 16; ++i) At[kq + i][r] = tmp[i];
    }
    {
      const int k  = tid >> 3;
      const int cq = (tid & 7) << 3;
      const float* wp = pW + (size_t)(k0 + k) * OUTn + cq;
      *(float4*)&Ws[k][cq]     = *(const float4*)wp;
      *(float4*)&Ws[k][cq + 4] = *(const float4*)(wp + 4);
    }
    __syncthreads();
    #pragma unroll
    for (int k = 0; k < 32; ++k) {
      float4 a0v = *(const float4*)&At[k][r0];
      float4 a1v = *(const float4*)&At[k][r0 + 4];
      float4 wv4 = *(const float4*)&Ws[k][c0];
      float av[8] = {a0v.x, a0v.y, a0v.z, a0v.w, a1v.x, a1v.y, a1v.z, a1v.w};
      float wq[4] = {wv4.x, wv4.y, wv4.z, wv4.w};
      #pragma unroll
      for (int i = 0; i < 8; ++i) {
        #pragma unroll
        for (int j = 0; j < 4; ++j) acc[i][j] += av[i] * wq[j];
      }
    }
    __syncthreads();
  }

  float a[8][4];
  #pragma unroll
  for (int i = 0; i < 8; ++i)
    #pragma unroll
    for (int j = 0; j < 4; ++j) a[i][j] = acc[i][j] + pb[c0 + j];

  if (NORM) {
    #pragma unroll
    for (int i = 0; i < 8; ++i) {
      float ss = a[i][0]*a[i][0] + a[i][1]*a[i][1] + a[i][2]*a[i][2] + a[i][3]*a[i][3];
      #pragma unroll
      for (int off = 1; off < 16; off <<= 1) ss += __shfl_xor(ss, off);
      float inv = 1.f / fmaxf(sqrtf(ss), 1e-12f);
      #pragma unroll
      for (int j = 0; j < 4; ++j) a[i][j] *= inv;
    }
  }

  #pragma unroll
  for (int i = 0; i < 8; ++i) {
    int row = row0 + r0 + i;
    if (row >= N) continue;
    #pragma unroll
    for (int j = 0; j < 4; ++j)
      out[(size_t)row * OUTn + c0 + j] = a[i][j];
  }
}

// ---- fallback edge-op dispatcher ----------------------------------------
static void run_edge_fb(hipStream_t stream, const int* ei,
                        const float* sdot, const float* ddot, const float* hsrc,
                        float* outb, int Ndst,
                        unsigned* mbuf, float* sden, float* ebuf)
{
  hipMemsetAsync(mbuf, 0, (size_t)Ndst * 4 * sizeof(unsigned), stream);
  edge_logit_max<<<(En + 255) / 256, 256, 0, stream>>>(ei, sdot, ddot, mbuf);
  hipMemsetAsync(sden, 0, (size_t)Ndst * 4 * sizeof(float), stream);
  edge_exp_sum<<<(En + 255) / 256, 256, 0, stream>>>(ei, sdot, ddot, mbuf, sden, ebuf);
  hipMemsetAsync(outb, 0, (size_t)Ndst * HIDn * sizeof(float), stream);
  edge_scatter<<<((size_t)En * 64 + 255) / 256, 256, 0, stream>>>(ei, hsrc, ebuf, sden, outb);
  relu_k<<<((size_t)Ndst * HIDn + 255) / 256, 256, 0, stream>>>(outb, Ndst * HIDn);
}

extern "C" void kernel_launch(void* const* d_in, const int* in_sizes, int n_in,
                              void* d_out, int out_size, void* d_ws, size_t ws_size,
                              hipStream_t stream)
{
  const float* xc    = (const float*)d_in[0];
  const float* xd    = (const float*)d_in[1];
  const int*   ei_cc = (const int*)d_in[2];
  const int*   ei_dc = (const int*)d_in[3];
  const int*   ei_cd = (const int*)d_in[4];
  const float* W1c = (const float*)d_in[5];  const float* b1c = (const float*)d_in[6];
  const float* W1d = (const float*)d_in[7];  const float* b1d = (const float*)d_in[8];
  const float* a1s_cc = (const float*)d_in[9];  const float* a1d_cc = (const float*)d_in[10];
  const float* a1s_dc = (const float*)d_in[11]; const float* a1d_dc = (const float*)d_in[12];
  const float* a1s_cd = (const float*)d_in[13]; const float* a1d_cd = (const float*)d_in[14];
  const float* k1W = (const float*)d_in[15]; const float* k1b = (const float*)d_in[16];
  const float* q1  = (const float*)d_in[17];
  const float* W2c = (const float*)d_in[18]; const float* b2c = (const float*)d_in[19];
  const float* W2d = (const float*)d_in[20]; const float* b2d = (const float*)d_in[21];
  const float* a2s_cc = (const float*)d_in[22]; const float* a2d_cc = (const float*)d_in[23];
  const float* a2s_dc = (const float*)d_in[24]; const float* a2d_dc = (const float*)d_in[25];
  const float* a2s_cd = (const float*)d_in[26]; const float* a2d_cd = (const float*)d_in[27];
  const float* k2W = (const float*)d_in[28]; const float* k2b = (const float*)d_in[29];
  const float* q2  = (const float*)d_in[30];
  const float* pW  = (const float*)d_in[31]; const float* pb  = (const float*)d_in[32];

  // ---------------- workspace layout (fp32) ----------------
  float* ws = (float*)d_ws;
  const size_t NB = (size_t)NCn * HIDn;           // 6,400,000 floats per node buffer
  float* B0 = ws;            // h buffers (fp16 in CSR mode, fp32 in fallback)
  float* B1 = ws + NB;
  float* B2 = ws + 2 * NB;
  float* B3 = ws + 3 * NB;
  float* B4 = ws + 4 * NB;
  float* sml = ws + 5 * NB;
  // six dot arrays (N*4 each)
  float* scc = sml;
  float* dcc = sml + 200000;
  float* ddc = sml + 400000;
  float* scd = sml + 600000;
  float* sdc = sml + 800000;
  float* dcd = sml + 1000000;
  float* scoreB = sml + 1200000;                 // [s0,s1,w0,w1, s0',s1',w0',w1']
  float* R0 = sml + 1200016;                     // CSR region (or fallback temps)
  // CSR sub-layout (ints): offs 150,012 | elist 1,200,000 | tmp 150,000
  int*  R0i = (int*)R0;
  int*  offsBase  = R0i;
  int*  elistBase = R0i + 150012;
  int*  tmpBase   = R0i + 1350012;
  // fallback temps overlay
  unsigned* mbuf = (unsigned*)R0;                // N*4
  float*    sden = R0 + 200000;                  // N*4
  float*    ebuf = R0 + 400000;                  // E*4

  const size_t REQ_FLOATS = 5 * NB + 1200016 + 1500012;   // 34,700,028 fl = 138.8 MB
  const bool useCsr = ws_size >= REQ_FLOATS * sizeof(float);

  if (useCsr) {
    hipMemsetAsync(tmpBase, 0, 150000 * sizeof(int), stream);
    hist3<<<(3 * En + 255) / 256, 256, 0, stream>>>(ei_cc, ei_dc, ei_cd, tmpBase);
    scan3<<<3, 1024, 0, stream>>>(tmpBase, offsBase);
    hipMemsetAsync(tmpBase, 0, 150000 * sizeof(int), stream);
    fill3<<<(3 * En + 255) / 256, 256, 0, stream>>>(ei_cc, ei_dc, ei_cd,
                                                    offsBase, tmpBase, elistBase);
  }

  hipMemsetAsync(scoreB, 0, 8 * sizeof(float), stream);

  const int NT128 = (NCn + 127) / 128;
  const dim3 gemmGrid(NT128, HIDn / 64);
  const int dotGrid = (NCn * 4 + 255) / 256;
  const int* offs0 = offsBase;
  const int* offs1 = offsBase + 50004;
  const int* offs2 = offsBase + 100008;
  const int* el0 = elistBase;
  const int* el1 = elistBase + En;
  const int* el2 = elistBase + 2 * (size_t)En;

  // per-layer edge-attention dispatcher (hc/hd are fp16 in CSR mode)
  auto edge_layer = [&](void* hc, void* hd, float* oCC, float* oDC, float* oCD) {
    if (useCsr) {
      EdgeOp o0{offs0, el0, scc, dcc, (const __half*)hc, oCC};
      EdgeOp o1{offs1, el1, sdc, ddc, (const __half*)hd, oDC};
      EdgeOp o2{offs2, el2, scd, dcd, (const __half*)hc, oCD};
      csr_att3<<<dim3((NCn + 3) / 4, 3), 256, 0, stream>>>(o0, o1, o2, NCn);
    } else {
      run_edge_fb(stream, ei_cc, scc, dcc, (const float*)hc, oCC, NCn, mbuf, sden, ebuf);
      run_edge_fb(stream, ei_dc, sdc, ddc, (const float*)hd, oDC, NCn, mbuf, sden, ebuf);
      run_edge_fb(stream, ei_cd, scd, dcd, (const float*)hc, oCD, NDn, mbuf, sden, ebuf);
    }
  };

  if (useCsr) {
    // ---------------- layer 1 (h in fp16) ----------------
    gemm_bias<256, 0, 1><<<gemmGrid, 256, 0, stream>>>(xc, nullptr, nullptr, W1c, b1c, B0, NCn, HIDn);
    gemm_bias<256, 0, 1><<<gemmGrid, 256, 0, stream>>>(xd, nullptr, nullptr, W1d, b1d, B1, NDn, HIDn);
    dot6<1><<<dotGrid, 256, 0, stream>>>(B0, B1, a1s_cc, a1d_cc, a1s_dc, a1d_dc, a1s_cd, a1d_cd,
                                         scc, dcc, ddc, scd, sdc, dcd, NCn);
    edge_layer(B0, B1, B2, B3, B4);
    score_gemm<<<dim3(NT128, 2, 2), 256, 0, stream>>>(B2, B3, k1W, k1b, q1, NCn, scoreB);
    softmax2_kernel<<<1, 1, 0, stream>>>(scoreB);

    // ---------------- layer 2 ----------------
    gemm_bias<128, 2, 1><<<gemmGrid, 256, 0, stream>>>(B2, B3, scoreB, W2c, b2c, B0, NCn, HIDn);
    gemm_bias<128, 1, 1><<<gemmGrid, 256, 0, stream>>>(B4, nullptr, nullptr, W2d, b2d, B1, NDn, HIDn);
    dot6<1><<<dotGrid, 256, 0, stream>>>(B0, B1, a2s_cc, a2d_cc, a2s_dc, a2d_dc, a2s_cd, a2d_cd,
                                         scc, dcc, ddc, scd, sdc, dcd, NCn);
    edge_layer(B0, B1, B2, B3, B4);
    score_gemm<<<dim3(NT128, 2, 2), 256, 0, stream>>>(B2, B3, k2W, k2b, q2, NCn, scoreB + 4);
    softmax2_kernel<<<1, 1, 0, stream>>>(scoreB + 4);
  } else {
    // ---------------- fp32 fallback ----------------
    gemm_bias<256, 0, 0><<<gemmGrid, 256, 0, stream>>>(xc, nullptr, nullptr, W1c, b1c, B0, NCn, HIDn);
    gemm_bias<256, 0, 0><<<gemmGrid, 256, 0, stream>>>(xd, nullptr, nullptr, W1d, b1d, B1, NDn, HIDn);
    dot6<0><<<dotGrid, 256, 0, stream>>>(B0, B1, a1s_cc, a1d_cc, a1s_dc, a1d_dc, a1s_cd, a1d_cd,
                                         scc, dcc, ddc, scd, sdc, dcd, NCn);
    edge_layer(B0, B1, B2, B3, B4);
    score_gemm<<<dim3(NT128, 2, 2), 256, 0, stream>>>(B2, B3, k1W, k1b, q1, NCn, scoreB);
    softmax2_kernel<<<1, 1, 0, stream>>>(scoreB);

    gemm_bias<128, 2, 0><<<gemmGrid, 256, 0, stream>>>(B2, B3, scoreB, W2c, b2c, B0, NCn, HIDn);
    gemm_bias<128, 1, 0><<<gemmGrid, 256, 0, stream>>>(B4, nullptr, nullptr, W2d, b2d, B1, NDn, HIDn);
    dot6<0><<<dotGrid, 256, 0, stream>>>(B0, B1, a2s_cc, a2d_cc, a2s_dc, a2d_dc, a2s_cd, a2d_cd,
                                         scc, dcc, ddc, scd, sdc, dcd, NCn);
    edge_layer(B0, B1, B2, B3, B4);
    score_gemm<<<dim3(NT128, 2, 2), 256, 0, stream>>>(B2, B3, k2W, k2b, q2, NCn, scoreB + 4);
    softmax2_kernel<<<1, 1, 0, stream>>>(scoreB + 4);
  }

  // ---------------- projection (+combine/elu fused) ----------------
  proj_gemm<2, true ><<<NT128, 256, 0, stream>>>(B2, B3, scoreB + 4, pW, pb, (float*)d_out, NCn);
  proj_gemm<1, false><<<NT128, 256, 0, stream>>>(B4, nullptr, nullptr, pW, pb,
                                                 (float*)d_out + (size_t)NCn * OUTn, NDn);
}

// Round 13
// 659.515 us; speedup vs baseline: 1.3179x; 1.0349x over previous
//
#include <hip/hip_runtime.h>
#include <hip/hip_fp16.h>
#include <cmath>

#define DEVI static __device__ __forceinline__

constexpr int HIDn = 128, OUTn = 64;
constexpr int NCn = 50000, NDn = 50000, En = 400000;

// monotonic float->uint mapping for atomicMax on floats (handles signs)
DEVI unsigned fmap(float f) {
  int i = __float_as_int(f);
  return (i < 0) ? ~((unsigned)i) : (((unsigned)i) | 0x80000000u);
}
DEVI float fdecode(unsigned u) {
  int i = (u & 0x80000000u) ? (int)(u & 0x7fffffffu) : (int)(~u);
  return __int_as_float(i);
}

DEVI float tanh_fast(float x) {           // 1 - 2/(e^{2x}+1); saturates correctly
  float e = __expf(2.f * x);
  return 1.f - __fdividef(2.f, e + 1.f);
}

// ---- vectorized 8-wide A-row load + fused transform (value-based) -------
// MODE: 0=plain, 1=elu(x), 2=elu(w2*a+w3*b).  base must be 16B-aligned.
template<int MODE>
DEVI void loadrow8(float* __restrict__ tmp,
                   const float* __restrict__ A, const float* __restrict__ A2,
                   float w2, float w3, size_t base)
{
  const float4* p = (const float4*)(A + base);
  float4 u0 = p[0], u1 = p[1];
  float v[8] = {u0.x, u0.y, u0.z, u0.w, u1.x, u1.y, u1.z, u1.w};
  if (MODE == 2) {
    const float4* q = (const float4*)(A2 + base);
    float4 t0 = q[0], t1 = q[1];
    float vb[8] = {t0.x, t0.y, t0.z, t0.w, t1.x, t1.y, t1.z, t1.w};
    #pragma unroll
    for (int i = 0; i < 8; ++i) v[i] = w2 * v[i] + w3 * vb[i];
  }
  if (MODE >= 1) {
    #pragma unroll
    for (int i = 0; i < 8; ++i) v[i] = (v[i] > 0.f) ? v[i] : (__expf(v[i]) - 1.f);
  }
  #pragma unroll
  for (int i = 0; i < 8; ++i) tmp[i] = v[i];
}

// ------- GEMM: C[N,128] = xform(A)[N,KI] @ W[KI,128] + b; 64x128 tile ----
// 256 threads, 4x8 acc/thread. grid = ceil(N/64). A read once (no col split).
// OUT16: write C as __half. NDOT: fused per-(row,head) dots with NDOT vectors.
template<int KI, int MODE, int OUT16, int NDOT>
__global__ __launch_bounds__(256)
void gemm_bias(const float* __restrict__ A, const float* __restrict__ A2,
               const float* __restrict__ wv,
               const float* __restrict__ W, const float* __restrict__ b,
               void* __restrict__ Cv, int N,
               const float* __restrict__ av0, const float* __restrict__ av1,
               const float* __restrict__ av2, const float* __restrict__ av3,
               float* __restrict__ do0, float* __restrict__ do1,
               float* __restrict__ do2, float* __restrict__ do3)
{
  __shared__ float At[32][68];    // A^T chunk: [k][row], 64 rows
  __shared__ float Ws[32][132];   // W chunk:   [k][col], 128 cols
  float w2 = 0.f, w3 = 0.f;
  if (MODE == 2) { w2 = wv[2]; w3 = wv[3]; }
  const int row0 = blockIdx.x * 64;
  const int tid  = threadIdx.x;
  const int r0 = (tid >> 4) << 2;     // 0..60 step 4
  const int c0 = (tid & 15) << 3;     // 0..120 step 8
  float acc[4][8] = {};

  for (int k0 = 0; k0 < KI; k0 += 32) {
    {
      const int r  = tid >> 2;
      const int kq = (tid & 3) << 3;
      const int row = row0 + r;
      float tmp[8];
      if (row < N) {
        loadrow8<MODE>(tmp, A, A2, w2, w3, (size_t)row * KI + k0 + kq);
      } else {
        #pragma unroll
        for (int i = 0; i < 8; ++i) tmp[i] = 0.f;
      }
      #pragma unroll
      for (int i = 0; i < 8; ++i) At[kq + i][r] = tmp[i];
    }
    {
      const int k  = tid >> 3;
      const int cq = (tid & 7) << 4;
      const float* wp = W + (size_t)(k0 + k) * 128 + cq;
      *(float4*)&Ws[k][cq]      = *(const float4*)wp;
      *(float4*)&Ws[k][cq + 4]  = *(const float4*)(wp + 4);
      *(float4*)&Ws[k][cq + 8]  = *(const float4*)(wp + 8);
      *(float4*)&Ws[k][cq + 12] = *(const float4*)(wp + 12);
    }
    __syncthreads();
    #pragma unroll
    for (int k = 0; k < 32; ++k) {
      float4 a4 = *(const float4*)&At[k][r0];
      float4 w0 = *(const float4*)&Ws[k][c0];
      float4 w1 = *(const float4*)&Ws[k][c0 + 4];
      float av[4] = {a4.x, a4.y, a4.z, a4.w};
      float wq[8] = {w0.x, w0.y, w0.z, w0.w, w1.x, w1.y, w1.z, w1.w};
      #pragma unroll
      for (int i = 0; i < 4; ++i) {
        #pragma unroll
        for (int j = 0; j < 8; ++j) acc[i][j] += av[i] * wq[j];
      }
    }
    __syncthreads();
  }

  // bias
  float bb[8];
  #pragma unroll
  for (int j = 0; j < 8; ++j) bb[j] = b[c0 + j];

  // fused dot vectors (each 128 floats; this thread's 8-col slice)
  float avv[(NDOT > 0) ? NDOT : 1][8];
  if (NDOT > 0) {
    const float* avp[4] = {av0, av1, av2, av3};
    #pragma unroll
    for (int v = 0; v < NDOT; ++v) {
      float4 x0 = *(const float4*)(avp[v] + c0);
      float4 x1 = *(const float4*)(avp[v] + c0 + 4);
      avv[v][0] = x0.x; avv[v][1] = x0.y; avv[v][2] = x0.z; avv[v][3] = x0.w;
      avv[v][4] = x1.x; avv[v][5] = x1.y; avv[v][6] = x1.z; avv[v][7] = x1.w;
    }
  }
  float* dop[4] = {do0, do1, do2, do3};
  const int lane = tid & 63;
  const int ht = (tid & 15) >> 2;     // head of this thread's col slice

  #pragma unroll
  for (int i = 0; i < 4; ++i) {
    const int row = row0 + r0 + i;
    const bool ok = row < N;
    float vrow[8];
    #pragma unroll
    for (int j = 0; j < 8; ++j) vrow[j] = acc[i][j] + bb[j];
    if (ok) {
      if (OUT16) {
        __half* C = (__half*)Cv;
        __half2* cp = (__half2*)(C + (size_t)row * 128 + c0);
        #pragma unroll
        for (int j = 0; j < 4; ++j) cp[j] = __floats2half2_rn(vrow[2*j], vrow[2*j+1]);
      } else {
        float* C = (float*)Cv;
        float* cp = C + (size_t)row * 128 + c0;
        #pragma unroll
        for (int j = 0; j < 8; ++j) cp[j] = vrow[j];
      }
    }
    if (NDOT > 0) {
      #pragma unroll
      for (int v = 0; v < NDOT; ++v) {
        float p = 0.f;
        #pragma unroll
        for (int j = 0; j < 8; ++j) p += vrow[j] * avv[v][j];
        p += __shfl_xor(p, 1);
        p += __shfl_xor(p, 2);
        if (ok && (lane & 3) == 0) dop[v][(size_t)row * 4 + ht] = p;
      }
    }
  }
}

// ================= CSR build, all 3 graphs batched =======================
__global__ void hist3(const int* __restrict__ ei0, const int* __restrict__ ei1,
                      const int* __restrict__ ei2, int* __restrict__ tmpBase)
{
  int gid = blockIdx.x * blockDim.x + threadIdx.x;
  if (gid >= 3 * En) return;
  int g = gid / En, e = gid - g * En;
  const int* ei = (g == 0) ? ei0 : (g == 1) ? ei1 : ei2;
  atomicAdd(&tmpBase[g * 50000 + ei[En + e]], 1);
}

// one block per graph (grid=3, block=1024)
__global__ void scan3(const int* __restrict__ tmpBase, int* __restrict__ offsBase)
{
  const int n = 50000;
  const int* deg = tmpBase + blockIdx.x * 50000;
  int* offs = offsBase + blockIdx.x * 50004;
  __shared__ int wsum[16];
  __shared__ int carry_sh;
  int tid = threadIdx.x;
  if (tid == 0) { carry_sh = 0; offs[0] = 0; }
  __syncthreads();
  const int nw = blockDim.x >> 6;
  int lane = tid & 63, w = tid >> 6;
  for (int base = 0; base < n; base += blockDim.x) {
    int i = base + tid;
    int v = (i < n) ? deg[i] : 0;
    int x = v;
    #pragma unroll
    for (int off = 1; off < 64; off <<= 1) {
      int y = __shfl_up(x, off);
      if (lane >= off) x += y;
    }
    if (lane == 63) wsum[w] = x;
    __syncthreads();
    if (tid == 0) {
      int s = carry_sh;
      for (int ww = 0; ww < nw; ++ww) { int t = wsum[ww]; wsum[ww] = s; s += t; }
      carry_sh = s;
    }
    __syncthreads();
    if (i < n) offs[i + 1] = wsum[w] + x;
    __syncthreads();
  }
}

__global__ void fill3(const int* __restrict__ ei0, const int* __restrict__ ei1,
                      const int* __restrict__ ei2, const int* __restrict__ offsBase,
                      int* __restrict__ cursorBase, int* __restrict__ elistBase)
{
  int gid = blockIdx.x * blockDim.x + threadIdx.x;
  if (gid >= 3 * En) return;
  int g = gid / En, e = gid - g * En;
  const int* ei = (g == 0) ? ei0 : (g == 1) ? ei1 : ei2;
  const int* offs = offsBase + g * 50004;
  int* cursor = cursorBase + g * 50000;
  int* elist = elistBase + (size_t)g * En;
  int s = ei[e], d = ei[En + e];
  int p = atomicAdd(&cursor[d], 1);
  elist[offs[d] + p] = s;
}

// ==== FUSED edge attention (CSR, fp16 h, lane-specialized softmax) =======
// Chunked 16 edges: lane computes exp for (edge=lane&15, head=lane>>4) —
// each (edge,head) computed ONCE. den via 16-lane butterfly (already the
// gather head for this lane). Gather pulls w with one shfl per edge.
struct EdgeOp {
  const int* offs; const int* elist;
  const float* sdot; const float* ddot;
  const __half* hsrc; float* out;
};

DEVI void csr_att_body(const EdgeOp& op, int dst, int lane)
{
  const int i0 = op.offs[dst], i1 = op.offs[dst + 1];
  const int hB = lane >> 4;
  const float ddv = op.ddot[dst * 4 + hB];
  const __half* hsrc = op.hsrc;
  const float* sdot = op.sdot;
  const int* el = op.elist;
  const int wsel = lane & 48;
  float den = 0.f, a0 = 0.f, a1 = 0.f;

  for (int base = i0; base < i1; base += 16) {
    int i = base + (lane & 15);
    int s_ = 0;
    float w = 0.f;
    if (i < i1) {
      s_ = el[i];
      float lv = sdot[s_ * 4 + hB] + ddv;
      lv = fminf(fmaxf(lv, 0.2f * lv), 80.f);
      w = __expf(lv);
    }
    // den: butterfly within each 16-lane head group
    float g = w;
    g += __shfl_xor(g, 1);
    g += __shfl_xor(g, 2);
    g += __shfl_xor(g, 4);
    g += __shfl_xor(g, 8);
    den += g;

    const int rem = min(16, i1 - base);
    int j = 0;
    for (; j + 2 <= rem; j += 2) {
      int sA = __shfl(s_, j);
      int sB = __shfl(s_, j + 1);
      float wA = __shfl(w, wsel | j);
      float wB = __shfl(w, wsel | (j + 1));
      float2 hA = __half22float2(*(const __half2*)(hsrc + (size_t)sA * HIDn + lane * 2));
      float2 hBv = __half22float2(*(const __half2*)(hsrc + (size_t)sB * HIDn + lane * 2));
      a0 += hA.x * wA + hBv.x * wB;
      a1 += hA.y * wA + hBv.y * wB;
    }
    if (j < rem) {
      int sA = __shfl(s_, j);
      float wA = __shfl(w, wsel | j);
      float2 hA = __half22float2(*(const __half2*)(hsrc + (size_t)sA * HIDn + lane * 2));
      a0 += hA.x * wA;
      a1 += hA.y * wA;
    }
  }
  float dinv = __fdividef(1.f, den + 1e-16f);
  float2 o2;
  o2.x = fmaxf(a0 * dinv, 0.f);
  o2.y = fmaxf(a1 * dinv, 0.f);
  *(float2*)(op.out + (size_t)dst * HIDn + lane * 2) = o2;
}

__global__ __launch_bounds__(256)
void csr_att3(EdgeOp op0, EdgeOp op1, EdgeOp op2, int Ndst)
{
  int wave = (blockIdx.x * 256 + threadIdx.x) >> 6;
  if (wave >= Ndst) return;
  const int lane = threadIdx.x & 63;
  if (blockIdx.y == 0)      csr_att_body(op0, wave, lane);
  else if (blockIdx.y == 1) csr_att_body(op1, wave, lane);
  else                      csr_att_body(op2, wave, lane);
}

// ---- fallback path (atomic scatter, fp32 h), used only if ws too small --
__global__ void edge_logit_max(const int* __restrict__ ei,
                               const float* __restrict__ sdot,
                               const float* __restrict__ ddot,
                               unsigned* __restrict__ m)
{
  int e = blockIdx.x * blockDim.x + threadIdx.x;
  if (e >= En) return;
  int s = ei[e], d = ei[En + e];
  #pragma unroll
  for (int hh = 0; hh < 4; ++hh) {
    float l = sdot[s * 4 + hh] + ddot[d * 4 + hh];
    l = (l > 0.f) ? l : 0.2f * l;
    atomicMax(&m[d * 4 + hh], fmap(l));
  }
}

__global__ void edge_exp_sum(const int* __restrict__ ei,
                             const float* __restrict__ sdot,
                             const float* __restrict__ ddot,
                             const unsigned* __restrict__ m,
                             float* __restrict__ sden,
                             float* __restrict__ ebuf)
{
  int e = blockIdx.x * blockDim.x + threadIdx.x;
  if (e >= En) return;
  int s = ei[e], d = ei[En + e];
  #pragma unroll
  for (int hh = 0; hh < 4; ++hh) {
    float l = sdot[s * 4 + hh] + ddot[d * 4 + hh];
    l = (l > 0.f) ? l : 0.2f * l;
    float ex = expf(fminf(l - fdecode(m[d * 4 + hh]), 0.f));
    ebuf[e * 4 + hh] = ex;
    atomicAdd(&sden[d * 4 + hh], ex);
  }
}

__global__ __launch_bounds__(256)
void edge_scatter(const int* __restrict__ ei, const float* __restrict__ hsrc,
                  const float* __restrict__ ebuf, const float* __restrict__ sden,
                  float* __restrict__ out)
{
  int gid  = blockIdx.x * 256 + threadIdx.x;
  int e    = gid >> 6;
  if (e >= En) return;
  int lane = gid & 63;
  int s = ei[e], d = ei[En + e];
  #pragma unroll
  for (int half = 0; half < 2; ++half) {
    int c  = lane + half * 64;
    int hh = c >> 5;
    float alpha = ebuf[e * 4 + hh] / (sden[d * 4 + hh] + 1e-16f);
    atomicAdd(&out[(size_t)d * HIDn + c], hsrc[(size_t)s * HIDn + c] * alpha);
  }
}

__global__ void relu_k(float* __restrict__ x, int n)
{
  int i = blockIdx.x * blockDim.x + threadIdx.x;
  if (i < n) x[i] = fmaxf(x[i], 0.f);
}

// ---- semantic-attention score, 64x128 tile, 4x8 acc ---------------------
// grid (ceil(N/64), 2 inputs); single pass over o.
__global__ __launch_bounds__(256)
void score_gemm(const float* __restrict__ oA, const float* __restrict__ oB,
                const float* __restrict__ kW, const float* __restrict__ kb,
                const float* __restrict__ q, int N, float* __restrict__ slots)
{
  __shared__ float At[32][68];
  __shared__ float Ws[32][132];
  __shared__ float partw[4];
  const float* o = blockIdx.y ? oB : oA;
  const int row0 = blockIdx.x * 64;
  const int tid  = threadIdx.x;
  const int r0 = (tid >> 4) << 2;
  const int c0 = (tid & 15) << 3;
  float acc[4][8] = {};

  for (int k0 = 0; k0 < 128; k0 += 32) {
    {
      const int r  = tid >> 2;
      const int kq = (tid & 3) << 3;
      const int row = row0 + r;
      float tmp[8];
      if (row < N) {
        loadrow8<0>(tmp, o, nullptr, 0.f, 0.f, (size_t)row * HIDn + k0 + kq);
      } else {
        #pragma unroll
        for (int i = 0; i < 8; ++i) tmp[i] = 0.f;
      }
      #pragma unroll
      for (int i = 0; i < 8; ++i) At[kq + i][r] = tmp[i];
    }
    {
      const int k  = tid >> 3;
      const int cq = (tid & 7) << 4;
      const float* wp = kW + (size_t)(k0 + k) * 128 + cq;
      *(float4*)&Ws[k][cq]      = *(const float4*)wp;
      *(float4*)&Ws[k][cq + 4]  = *(const float4*)(wp + 4);
      *(float4*)&Ws[k][cq + 8]  = *(const float4*)(wp + 8);
      *(float4*)&Ws[k][cq + 12] = *(const float4*)(wp + 12);
    }
    __syncthreads();
    #pragma unroll
    for (int k = 0; k < 32; ++k) {
      float4 a4 = *(const float4*)&At[k][r0];
      float4 w0 = *(const float4*)&Ws[k][c0];
      float4 w1 = *(const float4*)&Ws[k][c0 + 4];
      float av[4] = {a4.x, a4.y, a4.z, a4.w};
      float wq[8] = {w0.x, w0.y, w0.z, w0.w, w1.x, w1.y, w1.z, w1.w};
      #pragma unroll
      for (int i = 0; i < 4; ++i) {
        #pragma unroll
        for (int j = 0; j < 8; ++j) acc[i][j] += av[i] * wq[j];
      }
    }
    __syncthreads();
  }

  float sum = 0.f;
  #pragma unroll
  for (int i = 0; i < 4; ++i) {
    int row = row0 + r0 + i;
    if (row >= N) continue;
    #pragma unroll
    for (int j = 0; j < 8; ++j) {
      int col = c0 + j;
      sum += q[col] * tanh_fast(acc[i][j] + kb[col]);
    }
  }
  #pragma unroll
  for (int off = 32; off > 0; off >>= 1) sum += __shfl_down(sum, off);
  int wid = tid >> 6, lane = tid & 63;
  if (lane == 0) partw[wid] = sum;
  __syncthreads();
  if (tid == 0)
    atomicAdd(&slots[blockIdx.y],
              (partw[0] + partw[1] + partw[2] + partw[3]) * (1.f / (float)N));
}

__global__ void softmax2_kernel(float* sb)   // sb[0],sb[1] -> weights sb[2],sb[3]
{
  float s0 = sb[0], s1 = sb[1];
  float mx = fmaxf(s0, s1);
  float e0 = expf(s0 - mx), e1 = expf(s1 - mx);
  float inv = 1.f / (e0 + e1);
  sb[2] = e0 * inv;
  sb[3] = e1 * inv;
}

// ---- final projection, 128x64 tile, 8x4 acc, fused transform ------------
template<int MODE, bool NORM>
__global__ __launch_bounds__(256)
void proj_gemm(const float* __restrict__ fa, const float* __restrict__ fb,
               const float* __restrict__ wv,
               const float* __restrict__ pW, const float* __restrict__ pb,
               float* __restrict__ out, int N)
{
  __shared__ float At[32][132];
  __shared__ float Ws[32][68];
  float w2 = 0.f, w3 = 0.f;
  if (MODE == 2) { w2 = wv[2]; w3 = wv[3]; }
  const int row0 = blockIdx.x * 128;
  const int tid  = threadIdx.x;
  const int r0 = (tid >> 4) << 3;
  const int c0 = (tid & 15) << 2;     // 64 cols
  float acc[8][4] = {};

  for (int k0 = 0; k0 < 128; k0 += 32) {
    {
      const int r  = tid >> 1;
      const int kq = (tid & 1) << 4;
      const int row = row0 + r;
      float tmp[16];
      if (row < N) {
        loadrow8<MODE>(tmp,     fa, fb, w2, w3, (size_t)row * HIDn + k0 + kq);
        loadrow8<MODE>(tmp + 8, fa, fb, w2, w3, (size_t)row * HIDn + k0 + kq + 8);
      } else {
        #pragma unroll
        for (int i = 0; i < 16; ++i) tmp[i] = 0.f;
      }
      #pragma unroll
      for (int i = 0; i < 16; ++i) At[kq + i][r] = tmp[i];
    }
    {
      const int k  = tid >> 3;
      const int cq = (tid & 7) << 3;
      const float* wp = pW + (size_t)(k0 + k) * OUTn + cq;
      *(float4*)&Ws[k][cq]     = *(const float4*)wp;
      *(float4*)&Ws[k][cq + 4] = *(const float4*)(wp + 4);
    }
    __syncthreads();
    #pragma unroll
    for (int k = 0; k < 32; ++k) {
      float4 a0v = *(const float4*)&At[k][r0];
      float4 a1v = *(const float4*)&At[k][r0 + 4];
      float4 wv4 = *(const float4*)&Ws[k][c0];
      float av[8] = {a0v.x, a0v.y, a0v.z, a0v.w, a1v.x, a1v.y, a1v.z, a1v.w};
      float wq[4] = {wv4.x, wv4.y, wv4.z, wv4.w};
      #pragma unroll
      for (int i = 0; i < 8; ++i) {
        #pragma unroll
        for (int j = 0; j < 4; ++j) acc[i][j] += av[i] * wq[j];
      }
    }
    __syncthreads();
  }

  float a[8][4];
  #pragma unroll
  for (int i = 0; i < 8; ++i)
    #pragma unroll
    for (int j = 0; j < 4; ++j) a[i][j] = acc[i][j] + pb[c0 + j];

  if (NORM) {
    #pragma unroll
    for (int i = 0; i < 8; ++i) {
      float ss = a[i][0]*a[i][0] + a[i][1]*a[i][1] + a[i][2]*a[i][2] + a[i][3]*a[i][3];
      #pragma unroll
      for (int off = 1; off < 16; off <<= 1) ss += __shfl_xor(ss, off);
      float inv = 1.f / fmaxf(sqrtf(ss), 1e-12f);
      #pragma unroll
      for (int j = 0; j < 4; ++j) a[i][j] *= inv;
    }
  }

  #pragma unroll
  for (int i = 0; i < 8; ++i) {
    int row = row0 + r0 + i;
    if (row >= N) continue;
    #pragma unroll
    for (int j = 0; j < 4; ++j)
      out[(size_t)row * OUTn + c0 + j] = a[i][j];
  }
}

// ---- fallback edge-op dispatcher ----------------------------------------
static void run_edge_fb(hipStream_t stream, const int* ei,
                        const float* sdot, const float* ddot, const float* hsrc,
                        float* outb, int Ndst,
                        unsigned* mbuf, float* sden, float* ebuf)
{
  hipMemsetAsync(mbuf, 0, (size_t)Ndst * 4 * sizeof(unsigned), stream);
  edge_logit_max<<<(En + 255) / 256, 256, 0, stream>>>(ei, sdot, ddot, mbuf);
  hipMemsetAsync(sden, 0, (size_t)Ndst * 4 * sizeof(float), stream);
  edge_exp_sum<<<(En + 255) / 256, 256, 0, stream>>>(ei, sdot, ddot, mbuf, sden, ebuf);
  hipMemsetAsync(outb, 0, (size_t)Ndst * HIDn * sizeof(float), stream);
  edge_scatter<<<((size_t)En * 64 + 255) / 256, 256, 0, stream>>>(ei, hsrc, ebuf, sden, outb);
  relu_k<<<((size_t)Ndst * HIDn + 255) / 256, 256, 0, stream>>>(outb, Ndst * HIDn);
}

extern "C" void kernel_launch(void* const* d_in, const int* in_sizes, int n_in,
                              void* d_out, int out_size, void* d_ws, size_t ws_size,
                              hipStream_t stream)
{
  const float* xc    = (const float*)d_in[0];
  const float* xd    = (const float*)d_in[1];
  const int*   ei_cc = (const int*)d_in[2];
  const int*   ei_dc = (const int*)d_in[3];
  const int*   ei_cd = (const int*)d_in[4];
  const float* W1c = (const float*)d_in[5];  const float* b1c = (const float*)d_in[6];
  const float* W1d = (const float*)d_in[7];  const float* b1d = (const float*)d_in[8];
  const float* a1s_cc = (const float*)d_in[9];  const float* a1d_cc = (const float*)d_in[10];
  const float* a1s_dc = (const float*)d_in[11]; const float* a1d_dc = (const float*)d_in[12];
  const float* a1s_cd = (const float*)d_in[13]; const float* a1d_cd = (const float*)d_in[14];
  const float* k1W = (const float*)d_in[15]; const float* k1b = (const float*)d_in[16];
  const float* q1  = (const float*)d_in[17];
  const float* W2c = (const float*)d_in[18]; const float* b2c = (const float*)d_in[19];
  const float* W2d = (const float*)d_in[20]; const float* b2d = (const float*)d_in[21];
  const float* a2s_cc = (const float*)d_in[22]; const float* a2d_cc = (const float*)d_in[23];
  const float* a2s_dc = (const float*)d_in[24]; const float* a2d_dc = (const float*)d_in[25];
  const float* a2s_cd = (const float*)d_in[26]; const float* a2d_cd = (const float*)d_in[27];
  const float* k2W = (const float*)d_in[28]; const float* k2b = (const float*)d_in[29];
  const float* q2  = (const float*)d_in[30];
  const float* pW  = (const float*)d_in[31]; const float* pb  = (const float*)d_in[32];

  // ---------------- workspace layout (fp32) ----------------
  float* ws = (float*)d_ws;
  const size_t NB = (size_t)NCn * HIDn;           // 6,400,000 floats per node buffer
  float* B0 = ws;            // h buffers (fp16 in CSR mode, fp32 in fallback)
  float* B1 = ws + NB;
  float* B2 = ws + 2 * NB;
  float* B3 = ws + 3 * NB;
  float* B4 = ws + 4 * NB;
  float* sml = ws + 5 * NB;
  // six dot arrays (N*4 each)
  float* scc = sml;
  float* dcc = sml + 200000;
  float* ddc = sml + 400000;
  float* scd = sml + 600000;
  float* sdc = sml + 800000;
  float* dcd = sml + 1000000;
  float* scoreB = sml + 1200000;                 // [s0,s1,w0,w1, s0',s1',w0',w1']
  float* R0 = sml + 1200016;                     // CSR region (or fallback temps)
  // CSR sub-layout (ints): offs 150,012 | elist 1,200,000 | tmp 150,000
  int*  R0i = (int*)R0;
  int*  offsBase  = R0i;
  int*  elistBase = R0i + 150012;
  int*  tmpBase   = R0i + 1350012;
  // fallback temps overlay
  unsigned* mbuf = (unsigned*)R0;                // N*4
  float*    sden = R0 + 200000;                  // N*4
  float*    ebuf = R0 + 400000;                  // E*4

  const size_t REQ_FLOATS = 5 * NB + 1200016 + 1500012;   // 34,700,028 fl = 138.8 MB
  const bool useCsr = ws_size >= REQ_FLOATS * sizeof(float);

  if (useCsr) {
    hipMemsetAsync(tmpBase, 0, 150000 * sizeof(int), stream);
    hist3<<<(3 * En + 255) / 256, 256, 0, stream>>>(ei_cc, ei_dc, ei_cd, tmpBase);
    scan3<<<3, 1024, 0, stream>>>(tmpBase, offsBase);
    hipMemsetAsync(tmpBase, 0, 150000 * sizeof(int), stream);
    fill3<<<(3 * En + 255) / 256, 256, 0, stream>>>(ei_cc, ei_dc, ei_cd,
                                                    offsBase, tmpBase, elistBase);
  }

  hipMemsetAsync(scoreB, 0, 8 * sizeof(float), stream);

  const int NT64 = (NCn + 63) / 64;
  const int NT128 = (NCn + 127) / 128;
  const int* offs0 = offsBase;
  const int* offs1 = offsBase + 50004;
  const int* offs2 = offsBase + 100008;
  const int* el0 = elistBase;
  const int* el1 = elistBase + En;
  const int* el2 = elistBase + 2 * (size_t)En;

  // per-layer edge-attention dispatcher (hc/hd are fp16 in CSR mode)
  auto edge_layer = [&](void* hc, void* hd, float* oCC, float* oDC, float* oCD) {
    if (useCsr) {
      EdgeOp o0{offs0, el0, scc, dcc, (const __half*)hc, oCC};
      EdgeOp o1{offs1, el1, sdc, ddc, (const __half*)hd, oDC};
      EdgeOp o2{offs2, el2, scd, dcd, (const __half*)hc, oCD};
      csr_att3<<<dim3((NCn + 3) / 4, 3), 256, 0, stream>>>(o0, o1, o2, NCn);
    } else {
      run_edge_fb(stream, ei_cc, scc, dcc, (const float*)hc, oCC, NCn, mbuf, sden, ebuf);
      run_edge_fb(stream, ei_dc, sdc, ddc, (const float*)hd, oDC, NCn, mbuf, sden, ebuf);
      run_edge_fb(stream, ei_cd, scd, dcd, (const float*)hc, oCD, NDn, mbuf, sden, ebuf);
    }
  };

  if (useCsr) {
    // ---------------- layer 1 (h in fp16, dots fused) ----------------
    gemm_bias<256, 0, 1, 4><<<NT64, 256, 0, stream>>>(xc, nullptr, nullptr, W1c, b1c, B0, NCn,
                                                      a1s_cc, a1d_cc, a1d_dc, a1s_cd,
                                                      scc, dcc, ddc, scd);
    gemm_bias<256, 0, 1, 2><<<NT64, 256, 0, stream>>>(xd, nullptr, nullptr, W1d, b1d, B1, NDn,
                                                      a1s_dc, a1d_cd, nullptr, nullptr,
                                                      sdc, dcd, nullptr, nullptr);
    edge_layer(B0, B1, B2, B3, B4);
    score_gemm<<<dim3(NT64, 2), 256, 0, stream>>>(B2, B3, k1W, k1b, q1, NCn, scoreB);
    softmax2_kernel<<<1, 1, 0, stream>>>(scoreB);

    // ---------------- layer 2 ----------------
    gemm_bias<128, 2, 1, 4><<<NT64, 256, 0, stream>>>(B2, B3, scoreB, W2c, b2c, B0, NCn,
                                                      a2s_cc, a2d_cc, a2d_dc, a2s_cd,
                                                      scc, dcc, ddc, scd);
    gemm_bias<128, 1, 1, 2><<<NT64, 256, 0, stream>>>(B4, nullptr, nullptr, W2d, b2d, B1, NDn,
                                                      a2s_dc, a2d_cd, nullptr, nullptr,
                                                      sdc, dcd, nullptr, nullptr);
    edge_layer(B0, B1, B2, B3, B4);
    score_gemm<<<dim3(NT64, 2), 256, 0, stream>>>(B2, B3, k2W, k2b, q2, NCn, scoreB + 4);
    softmax2_kernel<<<1, 1, 0, stream>>>(scoreB + 4);
  } else {
    // ---------------- fp32 fallback ----------------
    gemm_bias<256, 0, 0, 4><<<NT64, 256, 0, stream>>>(xc, nullptr, nullptr, W1c, b1c, B0, NCn,
                                                      a1s_cc, a1d_cc, a1d_dc, a1s_cd,
                                                      scc, dcc, ddc, scd);
    gemm_bias<256, 0, 0, 2><<<NT64, 256, 0, stream>>>(xd, nullptr, nullptr, W1d, b1d, B1, NDn,
                                                      a1s_dc, a1d_cd, nullptr, nullptr,
                                                      sdc, dcd, nullptr, nullptr);
    edge_layer(B0, B1, B2, B3, B4);
    score_gemm<<<dim3(NT64, 2), 256, 0, stream>>>(B2, B3, k1W, k1b, q1, NCn, scoreB);
    softmax2_kernel<<<1, 1, 0, stream>>>(scoreB);

    gemm_bias<128, 2, 0, 4><<<NT64, 256, 0, stream>>>(B2, B3, scoreB, W2c, b2c, B0, NCn,
                                                      a2s_cc, a2d_cc, a2d_dc, a2s_cd,
                                                      scc, dcc, ddc, scd);
    gemm_bias<128, 1, 0, 2><<<NT64, 256, 0, stream>>>(B4, nullptr, nullptr, W2d, b2d, B1, NDn,
                                                      a2s_dc, a2d_cd, nullptr, nullptr,
                                                      sdc, dcd, nullptr, nullptr);
    edge_layer(B0, B1, B2, B3, B4);
    score_gemm<<<dim3(NT64, 2), 256, 0, stream>>>(B2, B3, k2W, k2b, q2, NCn, scoreB + 4);
    softmax2_kernel<<<1, 1, 0, stream>>>(scoreB + 4);
  }

  // ---------------- projection (+combine/elu fused) ----------------
  proj_gemm<2, true ><<<NT128, 256, 0, stream>>>(B2, B3, scoreB + 4, pW, pb, (float*)d_out, NCn);
  proj_gemm<1, false><<<NT128, 256, 0, stream>>>(B4, nullptr, nullptr, pW, pb,
                                                 (float*)d_out + (size_t)NCn * OUTn, NDn);
}

// Round 15
// 640.343 us; speedup vs baseline: 1.3574x; 1.0299x over previous
//
#include <hip/hip_runtime.h>
#include <hip/hip_fp16.h>
#include <cmath>

#define DEVI static __device__ __forceinline__

constexpr int HIDn = 128, OUTn = 64;
constexpr int NCn = 50000, NDn = 50000, En = 400000;

typedef __attribute__((ext_vector_type(8))) short bf16x8;
typedef __attribute__((ext_vector_type(4))) float f32x4;

// monotonic float->uint mapping for atomicMax on floats (handles signs)
DEVI unsigned fmap(float f) {
  int i = __float_as_int(f);
  return (i < 0) ? ~((unsigned)i) : (((unsigned)i) | 0x80000000u);
}
DEVI float fdecode(unsigned u) {
  int i = (u & 0x80000000u) ? (int)(u & 0x7fffffffu) : (int)(~u);
  return __int_as_float(i);
}

DEVI float tanh_fast(float x) {           // 1 - 2/(e^{2x}+1); saturates correctly
  float e = __expf(2.f * x);
  return 1.f - __fdividef(2.f, e + 1.f);
}

DEVI unsigned short f2bf(float x) {       // fp32 -> bf16 RNE
  unsigned u = __float_as_uint(x);
  return (unsigned short)((u + 0x7FFFu + ((u >> 16) & 1u)) >> 16);
}

// ---- vectorized 8-wide A-row load + fused transform (value-based) -------
// MODE: 0=plain, 1=elu(x), 2=elu(w2*a+w3*b).  base must be 16B-aligned.
template<int MODE>
DEVI void loadrow8(float* __restrict__ tmp,
                   const float* __restrict__ A, const float* __restrict__ A2,
                   float w2, float w3, size_t base)
{
  const float4* p = (const float4*)(A + base);
  float4 u0 = p[0], u1 = p[1];
  float v[8] = {u0.x, u0.y, u0.z, u0.w, u1.x, u1.y, u1.z, u1.w};
  if (MODE == 2) {
    const float4* q = (const float4*)(A2 + base);
    float4 t0 = q[0], t1 = q[1];
    float vb[8] = {t0.x, t0.y, t0.z, t0.w, t1.x, t1.y, t1.z, t1.w};
    #pragma unroll
    for (int i = 0; i < 8; ++i) v[i] = w2 * v[i] + w3 * vb[i];
  }
  if (MODE >= 1) {
    #pragma unroll
    for (int i = 0; i < 8; ++i) v[i] = (v[i] > 0.f) ? v[i] : (__expf(v[i]) - 1.f);
  }
  #pragma unroll
  for (int i = 0; i < 8; ++i) tmp[i] = v[i];
}

template<int MODE>
DEVI bf16x8 packrow8(const float* __restrict__ A, const float* __restrict__ A2,
                     float w2, float w3, size_t base)
{
  float t[8];
  loadrow8<MODE>(t, A, A2, w2, w3, base);
  bf16x8 r;
  #pragma unroll
  for (int i = 0; i < 8; ++i) r[i] = (short)f2bf(t[i]);
  return r;
}

// ------- GEMM: C[N,128] = xform(A)[N,KI] @ W[KI,128] + b; 64x128 tile ----
// (fp32 VALU path — fused per-(row,head) dots)
template<int KI, int MODE, int OUT16, int NDOT>
__global__ __launch_bounds__(256)
void gemm_bias(const float* __restrict__ A, const float* __restrict__ A2,
               const float* __restrict__ wv,
               const float* __restrict__ W, const float* __restrict__ b,
               void* __restrict__ Cv, int N,
               const float* __restrict__ av0, const float* __restrict__ av1,
               const float* __restrict__ av2, const float* __restrict__ av3,
               float* __restrict__ do0, float* __restrict__ do1,
               float* __restrict__ do2, float* __restrict__ do3)
{
  __shared__ float At[32][68];
  __shared__ float Ws[32][132];
  float w2 = 0.f, w3 = 0.f;
  if (MODE == 2) { w2 = wv[2]; w3 = wv[3]; }
  const int row0 = blockIdx.x * 64;
  const int tid  = threadIdx.x;
  const int r0 = (tid >> 4) << 2;
  const int c0 = (tid & 15) << 3;
  float acc[4][8] = {};

  for (int k0 = 0; k0 < KI; k0 += 32) {
    {
      const int r  = tid >> 2;
      const int kq = (tid & 3) << 3;
      const int row = row0 + r;
      float tmp[8];
      if (row < N) {
        loadrow8<MODE>(tmp, A, A2, w2, w3, (size_t)row * KI + k0 + kq);
      } else {
        #pragma unroll
        for (int i = 0; i < 8; ++i) tmp[i] = 0.f;
      }
      #pragma unroll
      for (int i = 0; i < 8; ++i) At[kq + i][r] = tmp[i];
    }
    {
      const int k  = tid >> 3;
      const int cq = (tid & 7) << 4;
      const float* wp = W + (size_t)(k0 + k) * 128 + cq;
      *(float4*)&Ws[k][cq]      = *(const float4*)wp;
      *(float4*)&Ws[k][cq + 4]  = *(const float4*)(wp + 4);
      *(float4*)&Ws[k][cq + 8]  = *(const float4*)(wp + 8);
      *(float4*)&Ws[k][cq + 12] = *(const float4*)(wp + 12);
    }
    __syncthreads();
    #pragma unroll
    for (int k = 0; k < 32; ++k) {
      float4 a4 = *(const float4*)&At[k][r0];
      float4 w0 = *(const float4*)&Ws[k][c0];
      float4 w1 = *(const float4*)&Ws[k][c0 + 4];
      float av[4] = {a4.x, a4.y, a4.z, a4.w};
      float wq[8] = {w0.x, w0.y, w0.z, w0.w, w1.x, w1.y, w1.z, w1.w};
      #pragma unroll
      for (int i = 0; i < 4; ++i) {
        #pragma unroll
        for (int j = 0; j < 8; ++j) acc[i][j] += av[i] * wq[j];
      }
    }
    __syncthreads();
  }

  float bb[8];
  #pragma unroll
  for (int j = 0; j < 8; ++j) bb[j] = b[c0 + j];

  float avv[(NDOT > 0) ? NDOT : 1][8];
  if (NDOT > 0) {
    const float* avp[4] = {av0, av1, av2, av3};
    #pragma unroll
    for (int v = 0; v < NDOT; ++v) {
      float4 x0 = *(const float4*)(avp[v] + c0);
      float4 x1 = *(const float4*)(avp[v] + c0 + 4);
      avv[v][0] = x0.x; avv[v][1] = x0.y; avv[v][2] = x0.z; avv[v][3] = x0.w;
      avv[v][4] = x1.x; avv[v][5] = x1.y; avv[v][6] = x1.z; avv[v][7] = x1.w;
    }
  }
  float* dop[4] = {do0, do1, do2, do3};
  const int lane = tid & 63;
  const int ht = (tid & 15) >> 2;

  #pragma unroll
  for (int i = 0; i < 4; ++i) {
    const int row = row0 + r0 + i;
    const bool ok = row < N;
    float vrow[8];
    #pragma unroll
    for (int j = 0; j < 8; ++j) vrow[j] = acc[i][j] + bb[j];
    if (ok) {
      if (OUT16) {
        __half* C = (__half*)Cv;
        __half2* cp = (__half2*)(C + (size_t)row * 128 + c0);
        #pragma unroll
        for (int j = 0; j < 4; ++j) cp[j] = __floats2half2_rn(vrow[2*j], vrow[2*j+1]);
      } else {
        float* C = (float*)Cv;
        float* cp = C + (size_t)row * 128 + c0;
        #pragma unroll
        for (int j = 0; j < 8; ++j) cp[j] = vrow[j];
      }
    }
    if (NDOT > 0) {
      #pragma unroll
      for (int v = 0; v < NDOT; ++v) {
        float p = 0.f;
        #pragma unroll
        for (int j = 0; j < 8; ++j) p += vrow[j] * avv[v][j];
        p += __shfl_xor(p, 1);
        p += __shfl_xor(p, 2);
        if (ok && (lane & 3) == 0) dop[v][(size_t)row * 4 + ht] = p;
      }
    }
  }
}

// ================= CSR build, all 3 graphs batched =======================
__global__ void hist3(const int* __restrict__ ei0, const int* __restrict__ ei1,
                      const int* __restrict__ ei2, int* __restrict__ tmpBase)
{
  int gid = blockIdx.x * blockDim.x + threadIdx.x;
  if (gid >= 3 * En) return;
  int g = gid / En, e = gid - g * En;
  const int* ei = (g == 0) ? ei0 : (g == 1) ? ei1 : ei2;
  atomicAdd(&tmpBase[g * 50000 + ei[En + e]], 1);
}

__global__ void scan3(const int* __restrict__ tmpBase, int* __restrict__ offsBase)
{
  const int n = 50000;
  const int* deg = tmpBase + blockIdx.x * 50000;
  int* offs = offsBase + blockIdx.x * 50004;
  __shared__ int wsum[16];
  __shared__ int carry_sh;
  int tid = threadIdx.x;
  if (tid == 0) { carry_sh = 0; offs[0] = 0; }
  __syncthreads();
  const int nw = blockDim.x >> 6;
  int lane = tid & 63, w = tid >> 6;
  for (int base = 0; base < n; base += blockDim.x) {
    int i = base + tid;
    int v = (i < n) ? deg[i] : 0;
    int x = v;
    #pragma unroll
    for (int off = 1; off < 64; off <<= 1) {
      int y = __shfl_up(x, off);
      if (lane >= off) x += y;
    }
    if (lane == 63) wsum[w] = x;
    __syncthreads();
    if (tid == 0) {
      int s = carry_sh;
      for (int ww = 0; ww < nw; ++ww) { int t = wsum[ww]; wsum[ww] = s; s += t; }
      carry_sh = s;
    }
    __syncthreads();
    if (i < n) offs[i + 1] = wsum[w] + x;
    __syncthreads();
  }
}

__global__ void fill3(const int* __restrict__ ei0, const int* __restrict__ ei1,
                      const int* __restrict__ ei2, const int* __restrict__ offsBase,
                      int* __restrict__ cursorBase, int* __restrict__ elistBase)
{
  int gid = blockIdx.x * blockDim.x + threadIdx.x;
  if (gid >= 3 * En) return;
  int g = gid / En, e = gid - g * En;
  const int* ei = (g == 0) ? ei0 : (g == 1) ? ei1 : ei2;
  const int* offs = offsBase + g * 50004;
  int* cursor = cursorBase + g * 50000;
  int* elist = elistBase + (size_t)g * En;
  int s = ei[e], d = ei[En + e];
  int p = atomicAdd(&cursor[d], 1);
  elist[offs[d] + p] = s;
}

// ---- W transpose+cast: W[128][KO] fp32 -> Wt[KO][128] bf16 --------------
__global__ void wtrans(const float* __restrict__ W, unsigned short* __restrict__ Wt, int KO)
{
  int idx = blockIdx.x * 256 + threadIdx.x;
  if (idx >= 128 * KO) return;
  int k = idx / KO, c = idx - k * KO;
  Wt[(size_t)c * 128 + k] = f2bf(W[idx]);
}

// ==== FUSED edge attention (CSR, fp16 h, lane-specialized softmax) =======
struct EdgeOp {
  const int* offs; const int* elist;
  const float* sdot; const float* ddot;
  const __half* hsrc; float* out;
};

DEVI void csr_att_body(const EdgeOp& op, int dst, int lane)
{
  const int i0 = op.offs[dst], i1 = op.offs[dst + 1];
  const int hB = lane >> 4;
  const float ddv = op.ddot[dst * 4 + hB];
  const __half* hsrc = op.hsrc;
  const float* sdot = op.sdot;
  const int* el = op.elist;
  const int wsel = lane & 48;
  float den = 0.f, a0 = 0.f, a1 = 0.f;

  for (int base = i0; base < i1; base += 16) {
    int i = base + (lane & 15);
    int s_ = 0;
    float w = 0.f;
    if (i < i1) {
      s_ = el[i];
      float lv = sdot[s_ * 4 + hB] + ddv;
      lv = fminf(fmaxf(lv, 0.2f * lv), 80.f);
      w = __expf(lv);
    }
    float g = w;
    g += __shfl_xor(g, 1);
    g += __shfl_xor(g, 2);
    g += __shfl_xor(g, 4);
    g += __shfl_xor(g, 8);
    den += g;

    const int rem = min(16, i1 - base);
    int j = 0;
    for (; j + 2 <= rem; j += 2) {
      int sA = __shfl(s_, j);
      int sB = __shfl(s_, j + 1);
      float wA = __shfl(w, wsel | j);
      float wB = __shfl(w, wsel | (j + 1));
      float2 hA = __half22float2(*(const __half2*)(hsrc + (size_t)sA * HIDn + lane * 2));
      float2 hBv = __half22float2(*(const __half2*)(hsrc + (size_t)sB * HIDn + lane * 2));
      a0 += hA.x * wA + hBv.x * wB;
      a1 += hA.y * wA + hBv.y * wB;
    }
    if (j < rem) {
      int sA = __shfl(s_, j);
      float wA = __shfl(w, wsel | j);
      float2 hA = __half22float2(*(const __half2*)(hsrc + (size_t)sA * HIDn + lane * 2));
      a0 += hA.x * wA;
      a1 += hA.y * wA;
    }
  }
  float dinv = __fdividef(1.f, den + 1e-16f);
  float2 o2;
  o2.x = fmaxf(a0 * dinv, 0.f);
  o2.y = fmaxf(a1 * dinv, 0.f);
  *(float2*)(op.out + (size_t)dst * HIDn + lane * 2) = o2;
}

__global__ __launch_bounds__(256)
void csr_att3(EdgeOp op0, EdgeOp op1, EdgeOp op2, int Ndst)
{
  int wave = (blockIdx.x * 256 + threadIdx.x) >> 6;
  if (wave >= Ndst) return;
  const int lane = threadIdx.x & 63;
  if (blockIdx.y == 0)      csr_att_body(op0, wave, lane);
  else if (blockIdx.y == 1) csr_att_body(op1, wave, lane);
  else                      csr_att_body(op2, wave, lane);
}

// ---- fallback path (atomic scatter, fp32 h), used only if ws too small --
__global__ void edge_logit_max(const int* __restrict__ ei,
                               const float* __restrict__ sdot,
                               const float* __restrict__ ddot,
                               unsigned* __restrict__ m)
{
  int e = blockIdx.x * blockDim.x + threadIdx.x;
  if (e >= En) return;
  int s = ei[e], d = ei[En + e];
  #pragma unroll
  for (int hh = 0; hh < 4; ++hh) {
    float l = sdot[s * 4 + hh] + ddot[d * 4 + hh];
    l = (l > 0.f) ? l : 0.2f * l;
    atomicMax(&m[d * 4 + hh], fmap(l));
  }
}

__global__ void edge_exp_sum(const int* __restrict__ ei,
                             const float* __restrict__ sdot,
                             const float* __restrict__ ddot,
                             const unsigned* __restrict__ m,
                             float* __restrict__ sden,
                             float* __restrict__ ebuf)
{
  int e = blockIdx.x * blockDim.x + threadIdx.x;
  if (e >= En) return;
  int s = ei[e], d = ei[En + e];
  #pragma unroll
  for (int hh = 0; hh < 4; ++hh) {
    float l = sdot[s * 4 + hh] + ddot[d * 4 + hh];
    l = (l > 0.f) ? l : 0.2f * l;
    float ex = expf(fminf(l - fdecode(m[d * 4 + hh]), 0.f));
    ebuf[e * 4 + hh] = ex;
    atomicAdd(&sden[d * 4 + hh], ex);
  }
}

__global__ __launch_bounds__(256)
void edge_scatter(const int* __restrict__ ei, const float* __restrict__ hsrc,
                  const float* __restrict__ ebuf, const float* __restrict__ sden,
                  float* __restrict__ out)
{
  int gid  = blockIdx.x * 256 + threadIdx.x;
  int e    = gid >> 6;
  if (e >= En) return;
  int lane = gid & 63;
  int s = ei[e], d = ei[En + e];
  #pragma unroll
  for (int half = 0; half < 2; ++half) {
    int c  = lane + half * 64;
    int hh = c >> 5;
    float alpha = ebuf[e * 4 + hh] / (sden[d * 4 + hh] + 1e-16f);
    atomicAdd(&out[(size_t)d * HIDn + c], hsrc[(size_t)s * HIDn + c] * alpha);
  }
}

__global__ void relu_k(float* __restrict__ x, int n)
{
  int i = blockIdx.x * blockDim.x + threadIdx.x;
  if (i < n) x[i] = fmaxf(x[i], 0.f);
}

// ---- semantic-attention score via MFMA bf16 -----------------------------
__global__ __launch_bounds__(256)
void score_mfma(const float* __restrict__ oA, const float* __restrict__ oB,
                const unsigned short* __restrict__ kWt,
                const float* __restrict__ kb, const float* __restrict__ q,
                int N, float* __restrict__ slots)
{
  __shared__ float partw[4];
  const float* o = blockIdx.y ? oB : oA;
  const int tid = threadIdx.x;
  const int w = tid >> 6, lane = tid & 63;
  const int row0 = (blockIdx.x * 4 + w) * 16;
  const int m = lane & 15, b = lane >> 4;
  const int arow = row0 + m;
  const bool rok = arow < N;

  const bf16x8 zfr = {0, 0, 0, 0, 0, 0, 0, 0};
  bf16x8 afr[4];
  {
    const size_t base = (size_t)arow * 128;
    #pragma unroll
    for (int ks = 0; ks < 4; ++ks) {
      if (rok) afr[ks] = packrow8<0>(o, nullptr, 0.f, 0.f, base + ks * 32 + b * 8);
      else     afr[ks] = zfr;
    }
  }

  float sum = 0.f;
  #pragma unroll
  for (int t = 0; t < 8; ++t) {
    f32x4 acc = {0.f, 0.f, 0.f, 0.f};
    const int col = t * 16 + m;
    const unsigned short* bp = kWt + (size_t)col * 128 + b * 8;
    #pragma unroll
    for (int ks = 0; ks < 4; ++ks)
      acc = __builtin_amdgcn_mfma_f32_16x16x32_bf16(afr[ks], *(const bf16x8*)(bp + ks * 32), acc, 0, 0, 0);
    const float qc = q[col], kbc = kb[col];
    #pragma unroll
    for (int r = 0; r < 4; ++r) {
      int row = row0 + b * 4 + r;
      if (row < N) sum += qc * tanh_fast(acc[r] + kbc);
    }
  }
  #pragma unroll
  for (int off = 32; off > 0; off >>= 1) sum += __shfl_down(sum, off);
  if (lane == 0) partw[w] = sum;
  __syncthreads();
  if (tid == 0)
    atomicAdd(&slots[blockIdx.y],
              (partw[0] + partw[1] + partw[2] + partw[3]) * (1.f / (float)N));
}

__global__ void softmax2_kernel(float* sb)   // sb[0],sb[1] -> weights sb[2],sb[3]
{
  float s0 = sb[0], s1 = sb[1];
  float mx = fmaxf(s0, s1);
  float e0 = expf(s0 - mx), e1 = expf(s1 - mx);
  float inv = 1.f / (e0 + e1);
  sb[2] = e0 * inv;
  sb[3] = e1 * inv;
}

// ---- final projection via MFMA bf16 (+ optional L2 norm) ----------------
template<int MODE, bool NORM>
__global__ __launch_bounds__(256)
void proj_mfma(const float* __restrict__ fa, const float* __restrict__ fb,
               const float* __restrict__ wv,
               const unsigned short* __restrict__ pWt, const float* __restrict__ pb,
               float* __restrict__ out, int N)
{
  float w2 = 0.f, w3 = 0.f;
  if (MODE == 2) { w2 = wv[2]; w3 = wv[3]; }
  const int tid = threadIdx.x;
  const int w = tid >> 6, lane = tid & 63;
  const int row0 = (blockIdx.x * 4 + w) * 16;
  const int m = lane & 15, b = lane >> 4;
  const int arow = row0 + m;
  const bool rok = arow < N;

  const bf16x8 zfr = {0, 0, 0, 0, 0, 0, 0, 0};
  bf16x8 afr[4];
  {
    const size_t base = (size_t)arow * 128;
    #pragma unroll
    for (int ks = 0; ks < 4; ++ks) {
      if (rok) afr[ks] = packrow8<MODE>(fa, fb, w2, w3, base + ks * 32 + b * 8);
      else     afr[ks] = zfr;
    }
  }

  f32x4 accs[4];
  float pbc[4];
  #pragma unroll
  for (int t = 0; t < 4; ++t) {
    f32x4 acc = {0.f, 0.f, 0.f, 0.f};
    const int col = t * 16 + m;
    const unsigned short* bp = pWt + (size_t)col * 128 + b * 8;
    #pragma unroll
    for (int ks = 0; ks < 4; ++ks)
      acc = __builtin_amdgcn_mfma_f32_16x16x32_bf16(afr[ks], *(const bf16x8*)(bp + ks * 32), acc, 0, 0, 0);
    accs[t] = acc;
    pbc[t] = pb[col];
  }

  #pragma unroll
  for (int r = 0; r < 4; ++r) {
    const int row = row0 + b * 4 + r;
    float v[4];
    #pragma unroll
    for (int t = 0; t < 4; ++t) v[t] = accs[t][r] + pbc[t];
    if (NORM) {
      float ss = v[0]*v[0] + v[1]*v[1] + v[2]*v[2] + v[3]*v[3];
      ss += __shfl_xor(ss, 1);
      ss += __shfl_xor(ss, 2);
      ss += __shfl_xor(ss, 4);
      ss += __shfl_xor(ss, 8);
      float inv = 1.f / fmaxf(sqrtf(ss), 1e-12f);
      #pragma unroll
      for (int t = 0; t < 4; ++t) v[t] *= inv;
    }
    if (row < N) {
      #pragma unroll
      for (int t = 0; t < 4; ++t)
        out[(size_t)row * OUTn + t * 16 + m] = v[t];
    }
  }
}

// ---- fallback edge-op dispatcher ----------------------------------------
static void run_edge_fb(hipStream_t stream, const int* ei,
                        const float* sdot, const float* ddot, const float* hsrc,
                        float* outb, int Ndst,
                        unsigned* mbuf, float* sden, float* ebuf)
{
  hipMemsetAsync(mbuf, 0, (size_t)Ndst * 4 * sizeof(unsigned), stream);
  edge_logit_max<<<(En + 255) / 256, 256, 0, stream>>>(ei, sdot, ddot, mbuf);
  hipMemsetAsync(sden, 0, (size_t)Ndst * 4 * sizeof(float), stream);
  edge_exp_sum<<<(En + 255) / 256, 256, 0, stream>>>(ei, sdot, ddot, mbuf, sden, ebuf);
  hipMemsetAsync(outb, 0, (size_t)Ndst * HIDn * sizeof(float), stream);
  edge_scatter<<<((size_t)En * 64 + 255) / 256, 256, 0, stream>>>(ei, hsrc, ebuf, sden, outb);
  relu_k<<<((size_t)Ndst * HIDn + 255) / 256, 256, 0, stream>>>(outb, Ndst * HIDn);
}

extern "C" void kernel_launch(void* const* d_in, const int* in_sizes, int n_in,
                              void* d_out, int out_size, void* d_ws, size_t ws_size,
                              hipStream_t stream)
{
  const float* xc    = (const float*)d_in[0];
  const float* xd    = (const float*)d_in[1];
  const int*   ei_cc = (const int*)d_in[2];
  const int*   ei_dc = (const int*)d_in[3];
  const int*   ei_cd = (const int*)d_in[4];
  const float* W1c = (const float*)d_in[5];  const float* b1c = (const float*)d_in[6];
  const float* W1d = (const float*)d_in[7];  const float* b1d = (const float*)d_in[8];
  const float* a1s_cc = (const float*)d_in[9];  const float* a1d_cc = (const float*)d_in[10];
  const float* a1s_dc = (const float*)d_in[11]; const float* a1d_dc = (const float*)d_in[12];
  const float* a1s_cd = (const float*)d_in[13]; const float* a1d_cd = (const float*)d_in[14];
  const float* k1W = (const float*)d_in[15]; const float* k1b = (const float*)d_in[16];
  const float* q1  = (const float*)d_in[17];
  const float* W2c = (const float*)d_in[18]; const float* b2c = (const float*)d_in[19];
  const float* W2d = (const float*)d_in[20]; const float* b2d = (const float*)d_in[21];
  const float* a2s_cc = (const float*)d_in[22]; const float* a2d_cc = (const float*)d_in[23];
  const float* a2s_dc = (const float*)d_in[24]; const float* a2d_dc = (const float*)d_in[25];
  const float* a2s_cd = (const float*)d_in[26]; const float* a2d_cd = (const float*)d_in[27];
  const float* k2W = (const float*)d_in[28]; const float* k2b = (const float*)d_in[29];
  const float* q2  = (const float*)d_in[30];
  const float* pW  = (const float*)d_in[31]; const float* pb  = (const float*)d_in[32];

  // ---------------- workspace layout (fp32) ----------------
  float* ws = (float*)d_ws;
  const size_t NB = (size_t)NCn * HIDn;
  float* B0 = ws;            // h buffers (fp16 in CSR mode, fp32 in fallback)
  float* B1 = ws + NB;
  float* B2 = ws + 2 * NB;
  float* B3 = ws + 3 * NB;
  float* B4 = ws + 4 * NB;
  float* sml = ws + 5 * NB;
  float* scc = sml;
  float* dcc = sml + 200000;
  float* ddc = sml + 400000;
  float* scd = sml + 600000;
  float* sdc = sml + 800000;
  float* dcd = sml + 1000000;
  float* scoreB = sml + 1200000;
  float* R0 = sml + 1200016;
  int*  R0i = (int*)R0;
  int*  offsBase  = R0i;                                   // 150,012 ints
  int*  elistBase = R0i + 150012;                          // 1,200,000 ints
  int*  tmpBase   = R0i + 1350012;                         // 150,000 ints
  unsigned short* kW1t = (unsigned short*)(R0i + 1500012); // 16384 halves
  unsigned short* kW2t = (unsigned short*)(R0i + 1508204); // 16384 halves
  unsigned short* pWt  = (unsigned short*)(R0i + 1516396); // 8192 halves
  // fallback temps overlay (over CSR region)
  unsigned* mbuf = (unsigned*)R0;
  float*    sden = R0 + 200000;
  float*    ebuf = R0 + 400000;

  const size_t REQ_FLOATS = 5 * NB + 1200016 + 1520492;    // 34,720,508 fl
  const bool useCsr = ws_size >= REQ_FLOATS * sizeof(float);

  if (useCsr) {
    hipMemsetAsync(tmpBase, 0, 150000 * sizeof(int), stream);
    hist3<<<(3 * En + 255) / 256, 256, 0, stream>>>(ei_cc, ei_dc, ei_cd, tmpBase);
    scan3<<<3, 1024, 0, stream>>>(tmpBase, offsBase);
    hipMemsetAsync(tmpBase, 0, 150000 * sizeof(int), stream);
    fill3<<<(3 * En + 255) / 256, 256, 0, stream>>>(ei_cc, ei_dc, ei_cd,
                                                    offsBase, tmpBase, elistBase);
  }
  // transpose+cast the three MFMA weight matrices
  wtrans<<<(128 * 128 + 255) / 256, 256, 0, stream>>>(k1W, kW1t, 128);
  wtrans<<<(128 * 128 + 255) / 256, 256, 0, stream>>>(k2W, kW2t, 128);
  wtrans<<<(128 * 64 + 255) / 256, 256, 0, stream>>>(pW, pWt, 64);

  hipMemsetAsync(scoreB, 0, 8 * sizeof(float), stream);

  const int NT64 = (NCn + 63) / 64;
  const int* offs0 = offsBase;
  const int* offs1 = offsBase + 50004;
  const int* offs2 = offsBase + 100008;
  const int* el0 = elistBase;
  const int* el1 = elistBase + En;
  const int* el2 = elistBase + 2 * (size_t)En;

  auto edge_layer = [&](void* hc, void* hd, float* oCC, float* oDC, float* oCD) {
    if (useCsr) {
      EdgeOp o0{offs0, el0, scc, dcc, (const __half*)hc, oCC};
      EdgeOp o1{offs1, el1, sdc, ddc, (const __half*)hd, oDC};
      EdgeOp o2{offs2, el2, scd, dcd, (const __half*)hc, oCD};
      csr_att3<<<dim3((NCn + 3) / 4, 3), 256, 0, stream>>>(o0, o1, o2, NCn);
    } else {
      run_edge_fb(stream, ei_cc, scc, dcc, (const float*)hc, oCC, NCn, mbuf, sden, ebuf);
      run_edge_fb(stream, ei_dc, sdc, ddc, (const float*)hd, oDC, NCn, mbuf, sden, ebuf);
      run_edge_fb(stream, ei_cd, scd, dcd, (const float*)hc, oCD, NDn, mbuf, sden, ebuf);
    }
  };

  if (useCsr) {
    // ---------------- layer 1 (h in fp16, dots fused) ----------------
    gemm_bias<256, 0, 1, 4><<<NT64, 256, 0, stream>>>(xc, nullptr, nullptr, W1c, b1c, B0, NCn,
                                                      a1s_cc, a1d_cc, a1d_dc, a1s_cd,
                                                      scc, dcc, ddc, scd);
    gemm_bias<256, 0, 1, 2><<<NT64, 256, 0, stream>>>(xd, nullptr, nullptr, W1d, b1d, B1, NDn,
                                                      a1s_dc, a1d_cd, nullptr, nullptr,
                                                      sdc, dcd, nullptr, nullptr);
    edge_layer(B0, B1, B2, B3, B4);
    score_mfma<<<dim3(NT64, 2), 256, 0, stream>>>(B2, B3, kW1t, k1b, q1, NCn, scoreB);
    softmax2_kernel<<<1, 1, 0, stream>>>(scoreB);

    // ---------------- layer 2 ----------------
    gemm_bias<128, 2, 1, 4><<<NT64, 256, 0, stream>>>(B2, B3, scoreB, W2c, b2c, B0, NCn,
                                                      a2s_cc, a2d_cc, a2d_dc, a2s_cd,
                                                      scc, dcc, ddc, scd);
    gemm_bias<128, 1, 1, 2><<<NT64, 256, 0, stream>>>(B4, nullptr, nullptr, W2d, b2d, B1, NDn,
                                                      a2s_dc, a2d_cd, nullptr, nullptr,
                                                      sdc, dcd, nullptr, nullptr);
    edge_layer(B0, B1, B2, B3, B4);
    score_mfma<<<dim3(NT64, 2), 256, 0, stream>>>(B2, B3, kW2t, k2b, q2, NCn, scoreB + 4);
    softmax2_kernel<<<1, 1, 0, stream>>>(scoreB + 4);
  } else {
    gemm_bias<256, 0, 0, 4><<<NT64, 256, 0, stream>>>(xc, nullptr, nullptr, W1c, b1c, B0, NCn,
                                                      a1s_cc, a1d_cc, a1d_dc, a1s_cd,
                                                      scc, dcc, ddc, scd);
    gemm_bias<256, 0, 0, 2><<<NT64, 256, 0, stream>>>(xd, nullptr, nullptr, W1d, b1d, B1, NDn,
                                                      a1s_dc, a1d_cd, nullptr, nullptr,
                                                      sdc, dcd, nullptr, nullptr);
    edge_layer(B0, B1, B2, B3, B4);
    score_mfma<<<dim3(NT64, 2), 256, 0, stream>>>(B2, B3, kW1t, k1b, q1, NCn, scoreB);
    softmax2_kernel<<<1, 1, 0, stream>>>(scoreB);

    gemm_bias<128, 2, 0, 4><<<NT64, 256, 0, stream>>>(B2, B3, scoreB, W2c, b2c, B0, NCn,
                                                      a2s_cc, a2d_cc, a2d_dc, a2s_cd,
                                                      scc, dcc, ddc, scd);
    gemm_bias<128, 1, 0, 2><<<NT64, 256, 0, stream>>>(B4, nullptr, nullptr, W2d, b2d, B1, NDn,
                                                      a2s_dc, a2d_cd, nullptr, nullptr,
                                                      sdc, dcd, nullptr, nullptr);
    edge_layer(B0, B1, B2, B3, B4);
    score_mfma<<<dim3(NT64, 2), 256, 0, stream>>>(B2, B3, kW2t, k2b, q2, NCn, scoreB + 4);
    softmax2_kernel<<<1, 1, 0, stream>>>(scoreB + 4);
  }

  // ---------------- projection (+combine/elu fused, MFMA) ----------------
  proj_mfma<2, true ><<<NT64, 256, 0, stream>>>(B2, B3, scoreB + 4, pWt, pb, (float*)d_out, NCn);
  proj_mfma<1, false><<<NT64, 256, 0, stream>>>(B4, nullptr, nullptr, pWt, pb,
                                                (float*)d_out + (size_t)NCn * OUTn, NDn);
}